// Round 2
// baseline (3293.885 us; speedup 1.0000x reference)
//
#include <hip/hip_runtime.h>

// KidneyEdgePredictor — edge-GNN, fp32 compute, bf16 h-storage.
// N=50000 nodes (D=13), E=1,280,000 edges, H=64.
// encoder(27->64) -> 3x conv(scatter-mean by dst/src) -> MLP 64->64->64->32->1.
//
// R1 changes vs R0 (which crashed with a GPU fault):
//  * workspace cut 379MB -> 215.4MB: h stored as bf16 (ws_size overflow was the
//    prime crash suspect). Everything else fp32.
//  * LDS cut 68.6KB -> 34.3KB per block: 2 waves/block (128 thr), grid doubled.
// Structure: lane = edge/node; acc[64] in VGPRs; activation scalar from
// conflict-free LDS (row pad 65); weight loads wave-uniform -> s_load + FMA.
// Scatter-mean via fp32 atomics into L2-resident [N,64] sums; mean folded in
// node matmul ((s@W)/cnt == (s/cnt)@W).

#define NN 50000
#define NE 1280000
#define PAD 65

#define WAVES 2
#define EDGE_ITERS 4
#define EDGE_BLOCKS 2500   // 20000 tiles / (2 waves * 4 iters)
#define NODE_BLOCKS 391    // ceil(782 node tiles / 2 waves)

typedef unsigned int   u32;
typedef unsigned short u16;

__device__ __forceinline__ float lrelu(float x) { return x >= 0.0f ? x : 0.2f * x; }
__device__ __forceinline__ float bf2f(u16 u) { return __uint_as_float(((u32)u) << 16); }
__device__ __forceinline__ u16 f2bf(float f) {             // round-to-nearest-even
    u32 b = __float_as_uint(f);
    return (u16)((b + 0x7FFFu + ((b >> 16) & 1u)) >> 16);
}

// stage one 64x64 bf16 tile (row-major, rows=edges) into fp32 LDS w/ PAD rows.
// writes are cross-lane: caller must __syncthreads() after.
__device__ __forceinline__ void stage_h_tile(float* __restrict__ buf,
                                             const u16* __restrict__ hm,
                                             long long e0, int lane)
{
    const uint4* hp = (const uint4*)(hm + e0 * 64);   // 16B = 8 bf16
#pragma unroll
    for (int i2 = 0; i2 < 8; ++i2) {
        const uint4 v = hp[i2 * 64 + lane];
        const int f = i2 * 512 + lane * 8;            // flat bf16 idx in tile
        const int r = f >> 6, c = f & 63;
        float* p = buf + r * PAD + c;
        const u32 u0 = v.x, u1 = v.y, u2 = v.z, u3 = v.w;
        p[0] = __uint_as_float(u0 << 16); p[1] = __uint_as_float(u0 & 0xFFFF0000u);
        p[2] = __uint_as_float(u1 << 16); p[3] = __uint_as_float(u1 & 0xFFFF0000u);
        p[4] = __uint_as_float(u2 << 16); p[5] = __uint_as_float(u2 & 0xFFFF0000u);
        p[6] = __uint_as_float(u3 << 16); p[7] = __uint_as_float(u3 & 0xFFFF0000u);
    }
}

// ---------------- encoder + scatter for conv1 + degree counts ----------------
__global__ void __launch_bounds__(128)
k_enc(const float* __restrict__ x, const int* __restrict__ ei,
      const float* __restrict__ raw, const float* __restrict__ wenc,
      const float* __restrict__ benc,
      u16* __restrict__ hm, float* __restrict__ s_in, float* __restrict__ s_out,
      float* __restrict__ cnt_in, float* __restrict__ cnt_out)
{
    __shared__ float buf[WAVES][64 * PAD];
    __shared__ int sidx[WAVES][64], didx[WAVES][64];
    const int w = threadIdx.x >> 6, lane = threadIdx.x & 63;

    for (int it = 0; it < EDGE_ITERS; ++it) {
        const int tile = (it * EDGE_BLOCKS + blockIdx.x) * WAVES + w;
        const long long e0 = (long long)tile * 64;

        const int ms = ei[e0 + lane];
        const int md = ei[NE + e0 + lane];
        sidx[w][lane] = ms;
        didx[w][lane] = md;
        atomicAdd(&cnt_in[md], 1.0f);    // once per edge; fp32 exact (<2^24)
        atomicAdd(&cnt_out[ms], 1.0f);

        // gather into MY row (lane-private: no barrier needed before matmul)
        float* row = buf[w] + lane * PAD;
#pragma unroll
        for (int j = 0; j < 13; ++j) row[j]      = x[ms * 13 + j];
#pragma unroll
        for (int j = 0; j < 13; ++j) row[13 + j] = x[md * 13 + j];
        row[26] = raw[e0 + lane];

        // lane = edge: acc[c] = b[c] + sum_k in[k]*W[k][c]  (W loads uniform)
        float acc[64];
#pragma unroll
        for (int c = 0; c < 64; ++c) acc[c] = benc[c];
        for (int k = 0; k < 27; ++k) {
            const float vk = row[k];
#pragma unroll
            for (int c = 0; c < 64; ++c) acc[c] += vk * wenc[k * 64 + c];
        }
#pragma unroll
        for (int c = 0; c < 64; ++c) row[c] = lrelu(acc[c]);
        __syncthreads();

        // channel-major writeback + scatter (coalesced rows)
        for (int i = 0; i < 64; ++i) {
            const int s = sidx[w][i], d = didx[w][i];
            const float v = buf[w][i * PAD + lane];
            hm[(e0 + i) * 64 + lane] = f2bf(v);
            atomicAdd(&s_in[d * 64 + lane], v);
            atomicAdd(&s_out[s * 64 + lane], v);
        }
        __syncthreads();
    }
}

// ---------------- node transform: t = (s @ W) * (1/max(cnt,1)) ----------------
__global__ void __launch_bounds__(128)
k_node(const float* __restrict__ s_in, const float* __restrict__ s_out,
       const float* __restrict__ cnt_in, const float* __restrict__ cnt_out,
       const float* __restrict__ w_in, const float* __restrict__ w_out,
       float* __restrict__ t_in, float* __restrict__ t_out)
{
    __shared__ float buf[WAVES][64 * PAD];
    const int w = threadIdx.x >> 6, lane = threadIdx.x & 63;
    const int tile = blockIdx.x * WAVES + w;   // up to 781; node 50047 max.
    const long long n0 = (long long)tile * 64; // overshoot loads stay inside ws;
                                               // stores are guarded by n < NN.
    for (int pass = 0; pass < 2; ++pass) {
        const float* sp = pass ? s_out : s_in;
        const float* wp = pass ? w_out : w_in;
        const float* cp = pass ? cnt_out : cnt_in;
        float* tp       = pass ? t_out : t_in;

        const float4* spp = (const float4*)(sp + n0 * 64);
#pragma unroll
        for (int i2 = 0; i2 < 16; ++i2) {
            const float4 v = spp[i2 * 64 + lane];
            const int f = i2 * 256 + lane * 4;
            const int r = f >> 6, c = f & 63;
            float* p = buf[w] + r * PAD + c;
            p[0] = v.x; p[1] = v.y; p[2] = v.z; p[3] = v.w;
        }
        __syncthreads();

        const float inv = 1.0f / fmaxf(cp[n0 + lane], 1.0f);
        float acc[64];
#pragma unroll
        for (int c = 0; c < 64; ++c) acc[c] = 0.0f;
        for (int k = 0; k < 64; ++k) {
            const float vk = buf[w][lane * PAD + k];
#pragma unroll
            for (int c = 0; c < 64; ++c) acc[c] += vk * wp[k * 64 + c];
        }
        float* row = buf[w] + lane * PAD;
#pragma unroll
        for (int c = 0; c < 64; ++c) row[c] = acc[c] * inv;
        __syncthreads();

        for (int i = 0; i < 64; ++i) {
            const long long n = n0 + i;
            if (n < NN) tp[n * 64 + lane] = buf[w][i * PAD + lane];
        }
        __syncthreads();
    }
}

// ---------------- conv edge update (+ optional scatter for next layer) ----------------
__global__ void __launch_bounds__(128)
k_edge(const float* __restrict__ wself, const float* __restrict__ bself,
       const float* __restrict__ t_in, const float* __restrict__ t_out,
       const int* __restrict__ ei, u16* __restrict__ hm,
       float* __restrict__ s_in, float* __restrict__ s_out, const int do_scatter)
{
    __shared__ float buf[WAVES][64 * PAD];
    __shared__ int sidx[WAVES][64], didx[WAVES][64];
    const int w = threadIdx.x >> 6, lane = threadIdx.x & 63;

    for (int it = 0; it < EDGE_ITERS; ++it) {
        const int tile = (it * EDGE_BLOCKS + blockIdx.x) * WAVES + w;
        const long long e0 = (long long)tile * 64;

        sidx[w][lane] = ei[e0 + lane];
        didx[w][lane] = ei[NE + e0 + lane];

        stage_h_tile(buf[w], hm, e0, lane);
        __syncthreads();

        float acc[64];
#pragma unroll
        for (int c = 0; c < 64; ++c) acc[c] = bself[c];
        for (int k = 0; k < 64; ++k) {
            const float vk = buf[w][lane * PAD + k];
#pragma unroll
            for (int c = 0; c < 64; ++c) acc[c] += vk * wself[k * 64 + c];
        }
        float* row = buf[w] + lane * PAD;
#pragma unroll
        for (int c = 0; c < 64; ++c) row[c] = acc[c];
        __syncthreads();

        // channel-major: + t_in[src] + t_out[dst], leaky, store bf16, scatter
        for (int i = 0; i < 64; ++i) {
            const int s = sidx[w][i], d = didx[w][i];
            float v = buf[w][i * PAD + lane]
                    + t_in[(long long)s * 64 + lane]
                    + t_out[(long long)d * 64 + lane];
            v = lrelu(v);
            hm[(e0 + i) * 64 + lane] = f2bf(v);
            if (do_scatter) {
                atomicAdd(&s_in[(long long)d * 64 + lane], v);
                atomicAdd(&s_out[(long long)s * 64 + lane], v);
            }
        }
        __syncthreads();
    }
}

// ---------------- MLP head: 64 -> 64 -> 64 -> 32 -> 1 ----------------
__global__ void __launch_bounds__(128)
k_mlp(const u16* __restrict__ hm,
      const float* __restrict__ w1, const float* __restrict__ b1,
      const float* __restrict__ w2, const float* __restrict__ b2,
      const float* __restrict__ w3, const float* __restrict__ b3,
      const float* __restrict__ w4, const float* __restrict__ b4,
      float* __restrict__ out)
{
    __shared__ float buf[WAVES][64 * PAD];
    const int w = threadIdx.x >> 6, lane = threadIdx.x & 63;

    for (int it = 0; it < EDGE_ITERS; ++it) {
        const int tile = (it * EDGE_BLOCKS + blockIdx.x) * WAVES + w;
        const long long e0 = (long long)tile * 64;

        stage_h_tile(buf[w], hm, e0, lane);
        __syncthreads();

        float* row = buf[w] + lane * PAD;   // lane-private from here on
        float acc[64];
        // L1
#pragma unroll
        for (int c = 0; c < 64; ++c) acc[c] = b1[c];
        for (int k = 0; k < 64; ++k) {
            const float vk = row[k];
#pragma unroll
            for (int c = 0; c < 64; ++c) acc[c] += vk * w1[k * 64 + c];
        }
#pragma unroll
        for (int c = 0; c < 64; ++c) row[c] = lrelu(acc[c]);
        // L2
#pragma unroll
        for (int c = 0; c < 64; ++c) acc[c] = b2[c];
        for (int k = 0; k < 64; ++k) {
            const float vk = row[k];
#pragma unroll
            for (int c = 0; c < 64; ++c) acc[c] += vk * w2[k * 64 + c];
        }
#pragma unroll
        for (int c = 0; c < 64; ++c) row[c] = lrelu(acc[c]);
        // L3: 64 -> 32
        float a3[32];
#pragma unroll
        for (int c = 0; c < 32; ++c) a3[c] = b3[c];
        for (int k = 0; k < 64; ++k) {
            const float vk = row[k];
#pragma unroll
            for (int c = 0; c < 32; ++c) a3[c] += vk * w3[k * 32 + c];
        }
        // L4: 32 -> 1
        float p0 = 0.f, p1 = 0.f, p2 = 0.f, p3 = 0.f;
#pragma unroll
        for (int k = 0; k < 32; k += 4) {
            p0 += lrelu(a3[k + 0]) * w4[k + 0];
            p1 += lrelu(a3[k + 1]) * w4[k + 1];
            p2 += lrelu(a3[k + 2]) * w4[k + 2];
            p3 += lrelu(a3[k + 3]) * w4[k + 3];
        }
        out[e0 + lane] = (p0 + p1) + (p2 + p3) + b4[0];
        __syncthreads();
    }
}

extern "C" void kernel_launch(void* const* d_in, const int* in_sizes, int n_in,
                              void* d_out, int out_size, void* d_ws, size_t ws_size,
                              hipStream_t stream)
{
    const float* x      = (const float*)d_in[0];
    const int*   ei     = (const int*)  d_in[1];
    const float* raw    = (const float*)d_in[2];
    const float* wenc   = (const float*)d_in[3];
    const float* benc   = (const float*)d_in[4];
    const float* wself1 = (const float*)d_in[5];
    const float* bself1 = (const float*)d_in[6];
    const float* win1   = (const float*)d_in[7];
    const float* wout1  = (const float*)d_in[8];
    const float* wself2 = (const float*)d_in[9];
    const float* bself2 = (const float*)d_in[10];
    const float* win2   = (const float*)d_in[11];
    const float* wout2  = (const float*)d_in[12];
    const float* wself3 = (const float*)d_in[13];
    const float* bself3 = (const float*)d_in[14];
    const float* win3   = (const float*)d_in[15];
    const float* wout3  = (const float*)d_in[16];
    const float* w1 = (const float*)d_in[17]; const float* b1 = (const float*)d_in[18];
    const float* w2 = (const float*)d_in[19]; const float* b2 = (const float*)d_in[20];
    const float* w3 = (const float*)d_in[21]; const float* b3 = (const float*)d_in[22];
    const float* w4 = (const float*)d_in[23]; const float* b4 = (const float*)d_in[24];

    // ws layout (fp32 region first, then bf16 h):
    //   s_in[3.2M] s_out[3.2M] cnt_in[50K] cnt_out[50K] t_in[3.2M] t_out[3.2M]
    //   = 12.9M floats (51.6MB), then h: NE*64 bf16 = 163.84MB. total 215.4MB.
    float* ws      = (float*)d_ws;
    float* s_in    = ws;
    float* s_out   = s_in  + (size_t)NN * 64;
    float* cnt_in  = s_out + (size_t)NN * 64;
    float* cnt_out = cnt_in + NN;
    float* t_in    = cnt_out + NN;
    float* t_out   = t_in  + (size_t)NN * 64;
    u16*   hm      = (u16*)(t_out + (size_t)NN * 64);

    // zero scatter sums + counts (ws is poisoned before every call)
    hipMemsetAsync(s_in, 0, ((size_t)NN * 64 * 2 + (size_t)NN * 2) * sizeof(float), stream);

    k_enc<<<EDGE_BLOCKS, 128, 0, stream>>>(x, ei, raw, wenc, benc, hm, s_in, s_out, cnt_in, cnt_out);

    k_node<<<NODE_BLOCKS, 128, 0, stream>>>(s_in, s_out, cnt_in, cnt_out, win1, wout1, t_in, t_out);
    hipMemsetAsync(s_in, 0, (size_t)NN * 64 * 2 * sizeof(float), stream);
    k_edge<<<EDGE_BLOCKS, 128, 0, stream>>>(wself1, bself1, t_in, t_out, ei, hm, s_in, s_out, 1);

    k_node<<<NODE_BLOCKS, 128, 0, stream>>>(s_in, s_out, cnt_in, cnt_out, win2, wout2, t_in, t_out);
    hipMemsetAsync(s_in, 0, (size_t)NN * 64 * 2 * sizeof(float), stream);
    k_edge<<<EDGE_BLOCKS, 128, 0, stream>>>(wself2, bself2, t_in, t_out, ei, hm, s_in, s_out, 1);

    k_node<<<NODE_BLOCKS, 128, 0, stream>>>(s_in, s_out, cnt_in, cnt_out, win3, wout3, t_in, t_out);
    k_edge<<<EDGE_BLOCKS, 128, 0, stream>>>(wself3, bself3, t_in, t_out, ei, hm, s_in, s_out, 0);

    k_mlp<<<EDGE_BLOCKS, 128, 0, stream>>>(hm, w1, b1, w2, b2, w3, b3, w4, b4, (float*)d_out);
}

// Round 3
// 2684.430 us; speedup vs baseline: 1.2270x; 1.2270x over previous
//
#include <hip/hip_runtime.h>

// KidneyEdgePredictor — edge-GNN, fp32 compute, bf16 h-storage, CSR aggregation.
// N=50000 nodes (D=13), E=1,280,000 edges, H=64.
// encoder(27->64) -> 3x conv(scatter-mean by dst/src) -> MLP 64->64->64->32->1.
//
// R2 post-mortem: k_edge 680us x3 with WRITE_SIZE=800MB (ideal 164MB) — the fp32
// scatter atomics (164M/layer) thrash L2/HBM. R3: build CSR (by-dst + by-src)
// once per call; aggregation = per-node gather-sum over bf16 h rows fused with
// the node matmul (k_agg). k_edge loses all atomics. conv3 fused with the MLP
// head (h3 never hits HBM). All edge-kernel LDS is wave-private -> no barriers.

#define NN 50000
#define NE 1280000
#define PAD 65
#define OFFSZ 50016          // off arrays padded for 16B ws alignment

#define WAVES 2
#define EDGE_ITERS 4
#define EDGE_BLOCKS 2500     // 20000 tiles / (2 waves * 4 iters)

typedef unsigned int   u32;
typedef unsigned short u16;

__device__ __forceinline__ float lrelu(float x) { return x >= 0.0f ? x : 0.2f * x; }
__device__ __forceinline__ float bf2f(u16 u) { return __uint_as_float(((u32)u) << 16); }
__device__ __forceinline__ u16 f2bf(float f) {             // round-to-nearest-even
    u32 b = __float_as_uint(f);
    return (u16)((b + 0x7FFFu + ((b >> 16) & 1u)) >> 16);
}

// stage one 64x64 bf16 tile (rows=edges) into fp32 LDS w/ PAD rows. Wave-private.
__device__ __forceinline__ void stage_h_tile(float* __restrict__ buf,
                                             const u16* __restrict__ hm,
                                             long long e0, int lane)
{
    const uint4* hp = (const uint4*)(hm + e0 * 64);   // 16B = 8 bf16
#pragma unroll
    for (int i2 = 0; i2 < 8; ++i2) {
        const uint4 v = hp[i2 * 64 + lane];
        const int f = i2 * 512 + lane * 8;            // flat bf16 idx in tile
        const int r = f >> 6, c = f & 63;
        float* p = buf + r * PAD + c;
        const u32 u0 = v.x, u1 = v.y, u2 = v.z, u3 = v.w;
        p[0] = __uint_as_float(u0 << 16); p[1] = __uint_as_float(u0 & 0xFFFF0000u);
        p[2] = __uint_as_float(u1 << 16); p[3] = __uint_as_float(u1 & 0xFFFF0000u);
        p[4] = __uint_as_float(u2 << 16); p[5] = __uint_as_float(u2 & 0xFFFF0000u);
        p[6] = __uint_as_float(u3 << 16); p[7] = __uint_as_float(u3 & 0xFFFF0000u);
    }
}

// ---------------- CSR build ----------------
__global__ void __launch_bounds__(256)
k_hist(const int* __restrict__ ei, int* __restrict__ deg_in, int* __restrict__ deg_out)
{
    const int e = blockIdx.x * 256 + threadIdx.x;     // grid == NE exactly
    atomicAdd(&deg_out[ei[e]], 1);
    atomicAdd(&deg_in[ei[NE + e]], 1);
}

// single block, 256 threads: exclusive scan of both degree arrays -> off + cursor
__global__ void __launch_bounds__(256)
k_scan(const int* __restrict__ deg_in, const int* __restrict__ deg_out,
       int* __restrict__ off_in, int* __restrict__ off_out,
       int* __restrict__ cur_in, int* __restrict__ cur_out)
{
    __shared__ int s[256];
    const int tid = threadIdx.x;
    const int CH = 196;                                // 256*196 = 50176 >= NN
    for (int pass = 0; pass < 2; ++pass) {
        const int* deg = pass ? deg_out : deg_in;
        int* off = pass ? off_out : off_in;
        int* cur = pass ? cur_out : cur_in;
        const int lo = tid * CH, hi = min(lo + CH, NN);
        int loc = 0;
        for (int i = lo; i < hi; ++i) loc += deg[i];
        s[tid] = loc;
        __syncthreads();
        for (int d = 1; d < 256; d <<= 1) {            // Hillis-Steele inclusive
            int t = (tid >= d) ? s[tid - d] : 0;
            __syncthreads();
            s[tid] += t;
            __syncthreads();
        }
        int run = s[tid] - loc;                        // exclusive base
        for (int i = lo; i < hi; ++i) { off[i] = run; cur[i] = run; run += deg[i]; }
        if (hi == NN) off[NN] = run;                   // == NE (thread 255 only)
        __syncthreads();
    }
}

__global__ void __launch_bounds__(256)
k_fill(const int* __restrict__ ei, int* __restrict__ cur_in, int* __restrict__ cur_out,
       int* __restrict__ csr_in, int* __restrict__ csr_out)
{
    const int e = blockIdx.x * 256 + threadIdx.x;
    int p = atomicAdd(&cur_out[ei[e]], 1);      csr_out[p] = e;
    int q = atomicAdd(&cur_in[ei[NE + e]], 1);  csr_in[q] = e;
}

// ---------------- encoder: h1 = lrelu([x_src|x_dst|raw] @ Wenc + b) ----------------
__global__ void __launch_bounds__(128)
k_enc(const float* __restrict__ x, const int* __restrict__ ei,
      const float* __restrict__ raw, const float* __restrict__ wenc,
      const float* __restrict__ benc, u16* __restrict__ hm)
{
    __shared__ float buf[WAVES][64 * PAD];
    const int w = threadIdx.x >> 6, lane = threadIdx.x & 63;

    for (int it = 0; it < EDGE_ITERS; ++it) {
        const int tile = (it * EDGE_BLOCKS + blockIdx.x) * WAVES + w;
        const long long e0 = (long long)tile * 64;

        const int ms = ei[e0 + lane];
        const int md = ei[NE + e0 + lane];

        float* row = buf[w] + lane * PAD;   // lane-private row
#pragma unroll
        for (int j = 0; j < 13; ++j) row[j]      = x[ms * 13 + j];
#pragma unroll
        for (int j = 0; j < 13; ++j) row[13 + j] = x[md * 13 + j];
        row[26] = raw[e0 + lane];

        float acc[64];
#pragma unroll
        for (int c = 0; c < 64; ++c) acc[c] = benc[c];
        for (int k = 0; k < 27; ++k) {
            const float vk = row[k];
#pragma unroll
            for (int c = 0; c < 64; ++c) acc[c] += vk * wenc[k * 64 + c];
        }
#pragma unroll
        for (int c = 0; c < 64; ++c) row[c] = lrelu(acc[c]);
        // wave-private LDS: lockstep wave64 + compiler lgkm ordering, no barrier
        for (int i = 0; i < 64; ++i)
            hm[(e0 + i) * 64 + lane] = f2bf(buf[w][i * PAD + lane]);
    }
}

// ---------------- per-node aggregate + transform: t = mean(h rows) @ W ----------------
__global__ void __launch_bounds__(256)
k_agg(const u16* __restrict__ hm,
      const int* __restrict__ off_in, const int* __restrict__ csr_in,
      const int* __restrict__ off_out, const int* __restrict__ csr_out,
      const float* __restrict__ w_in, const float* __restrict__ w_out,
      float* __restrict__ t_in, float* __restrict__ t_out)
{
    __shared__ float m[4][64];
    const int w = threadIdx.x >> 6, lane = threadIdx.x & 63;
    const int node = blockIdx.x * 4 + w;               // grid*4 == NN exactly

    for (int pass = 0; pass < 2; ++pass) {
        const int* off = pass ? off_out : off_in;
        const int* csr = pass ? csr_out : csr_in;
        const float* wp = pass ? w_out : w_in;
        float* tp       = pass ? t_out : t_in;

        const int b0 = off[node], b1 = off[node + 1];
        float s0 = 0.f, s1 = 0.f, s2 = 0.f, s3 = 0.f;
        int j = b0;
        for (; j + 4 <= b1; j += 4) {                  // 4 outstanding row loads
            const long long e0a = csr[j], e1a = csr[j + 1];
            const long long e2a = csr[j + 2], e3a = csr[j + 3];
            s0 += bf2f(hm[e0a * 64 + lane]);
            s1 += bf2f(hm[e1a * 64 + lane]);
            s2 += bf2f(hm[e2a * 64 + lane]);
            s3 += bf2f(hm[e3a * 64 + lane]);
        }
        for (; j < b1; ++j) s0 += bf2f(hm[(long long)csr[j] * 64 + lane]);

        const int deg = b1 - b0;
        const float inv = 1.0f / (float)(deg > 0 ? deg : 1);
        m[w][lane] = ((s0 + s1) + (s2 + s3)) * inv;    // wave-private, no barrier

        float acc = 0.f;
        for (int k = 0; k < 64; ++k) acc += m[w][k] * wp[k * 64 + lane];
        tp[(long long)node * 64 + lane] = acc;
    }
}

// ---------------- conv edge update (layers 1,2): h' = lrelu(h@Wself+b + t_in[s] + t_out[d]) ----------------
__global__ void __launch_bounds__(128)
k_edge(const float* __restrict__ wself, const float* __restrict__ bself,
       const float* __restrict__ t_in, const float* __restrict__ t_out,
       const int* __restrict__ ei, u16* __restrict__ hm)
{
    __shared__ float buf[WAVES][64 * PAD];
    __shared__ int sidx[WAVES][64], didx[WAVES][64];
    const int w = threadIdx.x >> 6, lane = threadIdx.x & 63;

    for (int it = 0; it < EDGE_ITERS; ++it) {
        const int tile = (it * EDGE_BLOCKS + blockIdx.x) * WAVES + w;
        const long long e0 = (long long)tile * 64;

        sidx[w][lane] = ei[e0 + lane];
        didx[w][lane] = ei[NE + e0 + lane];

        stage_h_tile(buf[w], hm, e0, lane);            // wave-private tile

        float acc[64];
#pragma unroll
        for (int c = 0; c < 64; ++c) acc[c] = bself[c];
        for (int k = 0; k < 64; ++k) {
            const float vk = buf[w][lane * PAD + k];
#pragma unroll
            for (int c = 0; c < 64; ++c) acc[c] += vk * wself[k * 64 + c];
        }
        float* row = buf[w] + lane * PAD;
#pragma unroll
        for (int c = 0; c < 64; ++c) row[c] = acc[c];

        // channel-major: + t_in[src] + t_out[dst], leaky, store bf16
        for (int i = 0; i < 64; ++i) {
            const int s = sidx[w][i], d = didx[w][i];
            float v = buf[w][i * PAD + lane]
                    + t_in[(long long)s * 64 + lane]
                    + t_out[(long long)d * 64 + lane];
            hm[(e0 + i) * 64 + lane] = f2bf(lrelu(v));
        }
    }
}

// ---------------- conv3 + MLP head fused (h3 never leaves the CU) ----------------
__global__ void __launch_bounds__(128)
k_edge_mlp(const float* __restrict__ wself, const float* __restrict__ bself,
           const float* __restrict__ t_in, const float* __restrict__ t_out,
           const int* __restrict__ ei, const u16* __restrict__ hm,
           const float* __restrict__ w1, const float* __restrict__ b1,
           const float* __restrict__ w2, const float* __restrict__ b2,
           const float* __restrict__ w3, const float* __restrict__ b3,
           const float* __restrict__ w4, const float* __restrict__ b4,
           float* __restrict__ out)
{
    __shared__ float buf[WAVES][64 * PAD];
    __shared__ int sidx[WAVES][64], didx[WAVES][64];
    const int w = threadIdx.x >> 6, lane = threadIdx.x & 63;

    for (int it = 0; it < EDGE_ITERS; ++it) {
        const int tile = (it * EDGE_BLOCKS + blockIdx.x) * WAVES + w;
        const long long e0 = (long long)tile * 64;

        sidx[w][lane] = ei[e0 + lane];
        didx[w][lane] = ei[NE + e0 + lane];

        stage_h_tile(buf[w], hm, e0, lane);

        float acc[64];
        // conv3 self matmul
#pragma unroll
        for (int c = 0; c < 64; ++c) acc[c] = bself[c];
        for (int k = 0; k < 64; ++k) {
            const float vk = buf[w][lane * PAD + k];
#pragma unroll
            for (int c = 0; c < 64; ++c) acc[c] += vk * wself[k * 64 + c];
        }
        float* row = buf[w] + lane * PAD;
#pragma unroll
        for (int c = 0; c < 64; ++c) row[c] = acc[c];

        // add aggregates channel-major, h3 back into LDS (no global store)
        for (int i = 0; i < 64; ++i) {
            const int s = sidx[w][i], d = didx[w][i];
            float v = buf[w][i * PAD + lane]
                    + t_in[(long long)s * 64 + lane]
                    + t_out[(long long)d * 64 + lane];
            buf[w][i * PAD + lane] = lrelu(v);
        }

        // MLP on my row (lane-private from here)
        // L1
#pragma unroll
        for (int c = 0; c < 64; ++c) acc[c] = b1[c];
        for (int k = 0; k < 64; ++k) {
            const float vk = row[k];
#pragma unroll
            for (int c = 0; c < 64; ++c) acc[c] += vk * w1[k * 64 + c];
        }
#pragma unroll
        for (int c = 0; c < 64; ++c) row[c] = lrelu(acc[c]);
        // L2
#pragma unroll
        for (int c = 0; c < 64; ++c) acc[c] = b2[c];
        for (int k = 0; k < 64; ++k) {
            const float vk = row[k];
#pragma unroll
            for (int c = 0; c < 64; ++c) acc[c] += vk * w2[k * 64 + c];
        }
#pragma unroll
        for (int c = 0; c < 64; ++c) row[c] = lrelu(acc[c]);
        // L3: 64 -> 32
        float a3[32];
#pragma unroll
        for (int c = 0; c < 32; ++c) a3[c] = b3[c];
        for (int k = 0; k < 64; ++k) {
            const float vk = row[k];
#pragma unroll
            for (int c = 0; c < 32; ++c) a3[c] += vk * w3[k * 32 + c];
        }
        // L4: 32 -> 1
        float p0 = 0.f, p1 = 0.f, p2 = 0.f, p3 = 0.f;
#pragma unroll
        for (int k = 0; k < 32; k += 4) {
            p0 += lrelu(a3[k + 0]) * w4[k + 0];
            p1 += lrelu(a3[k + 1]) * w4[k + 1];
            p2 += lrelu(a3[k + 2]) * w4[k + 2];
            p3 += lrelu(a3[k + 3]) * w4[k + 3];
        }
        out[e0 + lane] = (p0 + p1) + (p2 + p3) + b4[0];
    }
}

extern "C" void kernel_launch(void* const* d_in, const int* in_sizes, int n_in,
                              void* d_out, int out_size, void* d_ws, size_t ws_size,
                              hipStream_t stream)
{
    const float* x      = (const float*)d_in[0];
    const int*   ei     = (const int*)  d_in[1];
    const float* raw    = (const float*)d_in[2];
    const float* wenc   = (const float*)d_in[3];
    const float* benc   = (const float*)d_in[4];
    const float* wself1 = (const float*)d_in[5];
    const float* bself1 = (const float*)d_in[6];
    const float* win1   = (const float*)d_in[7];
    const float* wout1  = (const float*)d_in[8];
    const float* wself2 = (const float*)d_in[9];
    const float* bself2 = (const float*)d_in[10];
    const float* win2   = (const float*)d_in[11];
    const float* wout2  = (const float*)d_in[12];
    const float* wself3 = (const float*)d_in[13];
    const float* bself3 = (const float*)d_in[14];
    const float* win3   = (const float*)d_in[15];
    const float* wout3  = (const float*)d_in[16];
    const float* w1 = (const float*)d_in[17]; const float* b1 = (const float*)d_in[18];
    const float* w2 = (const float*)d_in[19]; const float* b2 = (const float*)d_in[20];
    const float* w3 = (const float*)d_in[21]; const float* b3 = (const float*)d_in[22];
    const float* w4 = (const float*)d_in[23]; const float* b4 = (const float*)d_in[24];

    // ws layout: t_in|t_out (fp32) · deg/cur/off/csr (int) · hm (bf16)
    // 25.6MB + 11.44MB + 163.84MB = 200.9MB  (hm offset 37,040,128 B, 16B-aligned)
    float* t_in    = (float*)d_ws;
    float* t_out   = t_in + (size_t)NN * 64;
    int*   deg_in  = (int*)(t_out + (size_t)NN * 64);
    int*   deg_out = deg_in + NN;
    int*   cur_in  = deg_out + NN;
    int*   cur_out = cur_in + NN;
    int*   off_in  = cur_out + NN;
    int*   off_out = off_in + OFFSZ;
    int*   csr_in  = off_out + OFFSZ;
    int*   csr_out = csr_in + NE;
    u16*   hm      = (u16*)(csr_out + NE);

    // CSR build (once per call; ws re-poisoned before every call)
    hipMemsetAsync(deg_in, 0, (size_t)2 * NN * sizeof(int), stream);
    k_hist<<<NE / 256, 256, 0, stream>>>(ei, deg_in, deg_out);
    k_scan<<<1, 256, 0, stream>>>(deg_in, deg_out, off_in, off_out, cur_in, cur_out);
    k_fill<<<NE / 256, 256, 0, stream>>>(ei, cur_in, cur_out, csr_in, csr_out);

    k_enc<<<EDGE_BLOCKS, 128, 0, stream>>>(x, ei, raw, wenc, benc, hm);

    k_agg<<<NN / 4, 256, 0, stream>>>(hm, off_in, csr_in, off_out, csr_out,
                                      win1, wout1, t_in, t_out);
    k_edge<<<EDGE_BLOCKS, 128, 0, stream>>>(wself1, bself1, t_in, t_out, ei, hm);

    k_agg<<<NN / 4, 256, 0, stream>>>(hm, off_in, csr_in, off_out, csr_out,
                                      win2, wout2, t_in, t_out);
    k_edge<<<EDGE_BLOCKS, 128, 0, stream>>>(wself2, bself2, t_in, t_out, ei, hm);

    k_agg<<<NN / 4, 256, 0, stream>>>(hm, off_in, csr_in, off_out, csr_out,
                                      win3, wout3, t_in, t_out);
    k_edge_mlp<<<EDGE_BLOCKS, 128, 0, stream>>>(wself3, bself3, t_in, t_out, ei, hm,
                                                w1, b1, w2, b2, w3, b3, w4, b4,
                                                (float*)d_out);
}

// Round 4
// 1463.143 us; speedup vs baseline: 2.2512x; 1.8347x over previous
//
#include <hip/hip_runtime.h>

// KidneyEdgePredictor — edge-GNN. bf16 h-storage + bf16 MFMA matmuls, fp32 gathers.
// N=50000 nodes (D=13), E=1,280,000 edges, H=64.
// encoder(27->64) -> 3x conv(scatter-mean by dst/src) -> MLP 64->64->64->32->1.
//
// R3 post-mortem: k_edge/k_edge_mlp latency-bound (VALUBusy 31%, HBM 5%, occ 19%).
// R4: (1) all 64x64 matmuls -> mfma_f32_16x16x32_bf16 (A-frags direct 16B loads
// from bf16 h; W->bf16 frags once per wave); (2) LDS tiles bf16 64x72 (9.2KB/wave,
// LDS no longer occupancy-binding); (3) t_in/t_out row gathers batched 16-deep
// for memory-level parallelism. CSR aggregation unchanged (R3 win).

#define NN 50000
#define NE 1280000
#define LDP 72               // u16 pitch: 144B rows -> 16B-aligned frag reads,
                             // conflict-free column (channel-major) access
#define OFFSZ 50016

#define WAVES 2
#define EDGE_ITERS 4
#define EDGE_BLOCKS 2500     // 20000 tiles / (2 waves * 4 iters)

typedef unsigned int   u32;
typedef unsigned short u16;
typedef __attribute__((ext_vector_type(8))) short  short8;   // 8 bf16 (4 VGPRs)
typedef __attribute__((ext_vector_type(4))) float  floatx4;  // MFMA acc

#define MFMA16(a, b, c) __builtin_amdgcn_mfma_f32_16x16x32_bf16(a, b, c, 0, 0, 0)

__device__ __forceinline__ float lrelu(float x) { return x >= 0.0f ? x : 0.2f * x; }
__device__ __forceinline__ float bf2f(u16 u) { return __uint_as_float(((u32)u) << 16); }
__device__ __forceinline__ u16 f2bf(float f) {               // RNE
    u32 b = __float_as_uint(f);
    return (u16)((b + 0x7FFFu + ((b >> 16) & 1u)) >> 16);
}

// B-frag: lane holds B[k0..k0+7][n] of a row-major fp32 weight (ld = row stride)
__device__ __forceinline__ short8 bfrag(const float* __restrict__ W, int ld, int n, int k0) {
    short8 b;
#pragma unroll
    for (int j = 0; j < 8; ++j) b[j] = (short)f2bf(W[(k0 + j) * ld + n]);
    return b;
}

// C(64x64) += A(64x64 from bf16 LDS tile) @ B(frags): 4 mtiles x 4 ntiles x 2 ksteps
__device__ __forceinline__ void mm_tile(const u16* __restrict__ tb,
                                        const short8 wf[2][4],
                                        floatx4 acc[4][4], int c16, int q4) {
#pragma unroll
    for (int mt = 0; mt < 4; ++mt) {
        const short8 a0 = *(const short8*)(tb + (mt * 16 + c16) * LDP + q4 * 8);
        const short8 a1 = *(const short8*)(tb + (mt * 16 + c16) * LDP + 32 + q4 * 8);
#pragma unroll
        for (int nt = 0; nt < 4; ++nt) {
            acc[mt][nt] = MFMA16(a0, wf[0][nt], acc[mt][nt]);
            acc[mt][nt] = MFMA16(a1, wf[1][nt], acc[mt][nt]);
        }
    }
}

// ---------------- CSR build ----------------
__global__ void __launch_bounds__(256)
k_hist(const int* __restrict__ ei, int* __restrict__ deg_in, int* __restrict__ deg_out)
{
    const int e = blockIdx.x * 256 + threadIdx.x;     // grid == NE exactly
    atomicAdd(&deg_out[ei[e]], 1);
    atomicAdd(&deg_in[ei[NE + e]], 1);
}

__global__ void __launch_bounds__(1024)
k_scan(const int* __restrict__ deg_in, const int* __restrict__ deg_out,
       int* __restrict__ off_in, int* __restrict__ off_out,
       int* __restrict__ cur_in, int* __restrict__ cur_out)
{
    __shared__ int s[1024];
    const int tid = threadIdx.x;
    const int CH = 49;                                 // 1024*49 = 50176 >= NN
    for (int pass = 0; pass < 2; ++pass) {
        const int* deg = pass ? deg_out : deg_in;
        int* off = pass ? off_out : off_in;
        int* cur = pass ? cur_out : cur_in;
        const int lo = tid * CH, hi = min(lo + CH, NN);
        int loc = 0;
        for (int i = lo; i < hi; ++i) loc += deg[i];
        s[tid] = loc;
        __syncthreads();
        for (int d = 1; d < 1024; d <<= 1) {           // Hillis-Steele inclusive
            int t = (tid >= d) ? s[tid - d] : 0;
            __syncthreads();
            s[tid] += t;
            __syncthreads();
        }
        int run = s[tid] - loc;                        // exclusive base
        for (int i = lo; i < hi; ++i) { off[i] = run; cur[i] = run; run += deg[i]; }
        if (hi == NN && lo < NN) off[NN] = run;        // == NE
        __syncthreads();
    }
}

__global__ void __launch_bounds__(256)
k_fill(const int* __restrict__ ei, int* __restrict__ cur_in, int* __restrict__ cur_out,
       int* __restrict__ csr_in, int* __restrict__ csr_out)
{
    const int e = blockIdx.x * 256 + threadIdx.x;
    int p = atomicAdd(&cur_out[ei[e]], 1);      csr_out[p] = e;
    int q = atomicAdd(&cur_in[ei[NE + e]], 1);  csr_in[q] = e;
}

// ---------------- encoder: h1 = lrelu([x_src|x_dst|raw] @ Wenc + b) ----------------
__global__ void __launch_bounds__(128)
k_enc(const float* __restrict__ x, const int* __restrict__ ei,
      const float* __restrict__ raw, const float* __restrict__ wenc,
      const float* __restrict__ benc, u16* __restrict__ hm)
{
    __shared__ alignas(16) u16 tile[WAVES][64 * LDP];
    const int w = threadIdx.x >> 6, lane = threadIdx.x & 63;

    for (int it = 0; it < EDGE_ITERS; ++it) {
        const int tileId = (it * EDGE_BLOCKS + blockIdx.x) * WAVES + w;
        const int e0 = tileId * 64;

        const int ms = ei[e0 + lane];
        const int md = ei[NE + e0 + lane];

        float f[27];                                   // features in registers
#pragma unroll
        for (int j = 0; j < 13; ++j) f[j]      = x[ms * 13 + j];
#pragma unroll
        for (int j = 0; j < 13; ++j) f[13 + j] = x[md * 13 + j];
        f[26] = raw[e0 + lane];

        float acc[64];
#pragma unroll
        for (int c = 0; c < 64; ++c) acc[c] = benc[c];
        for (int k = 0; k < 27; ++k) {
            const float vk = f[k];
#pragma unroll
            for (int c = 0; c < 64; ++c) acc[c] += vk * wenc[k * 64 + c];
        }
#pragma unroll
        for (int c = 0; c < 64; ++c) tile[w][lane * LDP + c] = f2bf(lrelu(acc[c]));
        // wave-private LDS, lockstep wave64: no barrier. channel-major store.
        for (int i = 0; i < 64; ++i)
            hm[(size_t)(e0 + i) * 64 + lane] = tile[w][i * LDP + lane];
    }
}

// ---------------- per-node aggregate + transform: t = mean(h rows) @ W ----------------
__global__ void __launch_bounds__(256)
k_agg(const u16* __restrict__ hm,
      const int* __restrict__ off_in, const int* __restrict__ csr_in,
      const int* __restrict__ off_out, const int* __restrict__ csr_out,
      const float* __restrict__ w_in, const float* __restrict__ w_out,
      float* __restrict__ t_in, float* __restrict__ t_out)
{
    __shared__ float m[4][64];
    const int w = threadIdx.x >> 6, lane = threadIdx.x & 63;
    const int node = blockIdx.x * 4 + w;               // grid*4 == NN exactly

    for (int pass = 0; pass < 2; ++pass) {
        const int* off = pass ? off_out : off_in;
        const int* csr = pass ? csr_out : csr_in;
        const float* wp = pass ? w_out : w_in;
        float* tp       = pass ? t_out : t_in;

        const int b0 = off[node], b1 = off[node + 1];
        float s0=0.f,s1=0.f,s2=0.f,s3=0.f,s4=0.f,s5=0.f,s6=0.f,s7=0.f;
        int j = b0;
        for (; j + 8 <= b1; j += 8) {                  // 8 outstanding row loads
            s0 += bf2f(hm[(size_t)csr[j+0] * 64 + lane]);
            s1 += bf2f(hm[(size_t)csr[j+1] * 64 + lane]);
            s2 += bf2f(hm[(size_t)csr[j+2] * 64 + lane]);
            s3 += bf2f(hm[(size_t)csr[j+3] * 64 + lane]);
            s4 += bf2f(hm[(size_t)csr[j+4] * 64 + lane]);
            s5 += bf2f(hm[(size_t)csr[j+5] * 64 + lane]);
            s6 += bf2f(hm[(size_t)csr[j+6] * 64 + lane]);
            s7 += bf2f(hm[(size_t)csr[j+7] * 64 + lane]);
        }
        for (; j < b1; ++j) s0 += bf2f(hm[(size_t)csr[j] * 64 + lane]);

        const int deg = b1 - b0;
        const float inv = 1.0f / (float)(deg > 0 ? deg : 1);
        m[w][lane] = (((s0+s1)+(s2+s3)) + ((s4+s5)+(s6+s7))) * inv;  // wave-private

        float acc = 0.f;
        for (int k = 0; k < 64; ++k) acc += m[w][k] * wp[k * 64 + lane];
        tp[(size_t)node * 64 + lane] = acc;
    }
}

// ---------------- conv edge update (layers 1,2), MFMA ----------------
__global__ void __launch_bounds__(128, 3)
k_edge(const float* __restrict__ wself, const float* __restrict__ bself,
       const float* __restrict__ t_in, const float* __restrict__ t_out,
       const int* __restrict__ ei, u16* __restrict__ hm)
{
    __shared__ alignas(16) u16 tile[WAVES][64 * LDP];
    __shared__ int sidx[WAVES][64], didx[WAVES][64];
    const int w = threadIdx.x >> 6, lane = threadIdx.x & 63;
    const int c16 = lane & 15, q4 = lane >> 4;

    short8 wf[2][4];                                   // Wself bf16 frags, resident
    float bias[4];
#pragma unroll
    for (int ks = 0; ks < 2; ++ks)
#pragma unroll
        for (int nt = 0; nt < 4; ++nt)
            wf[ks][nt] = bfrag(wself, 64, nt * 16 + c16, ks * 32 + q4 * 8);
#pragma unroll
    for (int nt = 0; nt < 4; ++nt) bias[nt] = bself[nt * 16 + c16];

    for (int it = 0; it < EDGE_ITERS; ++it) {
        const int tileId = (it * EDGE_BLOCKS + blockIdx.x) * WAVES + w;
        const int e0 = tileId * 64;
        sidx[w][lane] = ei[e0 + lane];
        didx[w][lane] = ei[NE + e0 + lane];

        floatx4 acc[4][4];
#pragma unroll
        for (int mt = 0; mt < 4; ++mt)
#pragma unroll
            for (int nt = 0; nt < 4; ++nt) acc[mt][nt] = (floatx4)(0.0f);

        // A-frags: direct 16B loads from bf16 h rows (consumed by MFMA before
        // this iteration's h stores -> no same-address hazard)
#pragma unroll
        for (int mt = 0; mt < 4; ++mt) {
            const short8* ap = (const short8*)(hm + (size_t)(e0 + mt * 16 + c16) * 64 + q4 * 8);
            const short8 a0 = ap[0];
            const short8 a1 = ap[4];                   // +32 bf16 = kstep 1
#pragma unroll
            for (int nt = 0; nt < 4; ++nt) {
                acc[mt][nt] = MFMA16(a0, wf[0][nt], acc[mt][nt]);
                acc[mt][nt] = MFMA16(a1, wf[1][nt], acc[mt][nt]);
            }
        }
        // C/D -> bf16 LDS tile (+bias), row=(lane>>4)*4+r, col=lane&15
#pragma unroll
        for (int mt = 0; mt < 4; ++mt)
#pragma unroll
            for (int nt = 0; nt < 4; ++nt)
#pragma unroll
                for (int r = 0; r < 4; ++r)
                    tile[w][(mt * 16 + q4 * 4 + r) * LDP + nt * 16 + c16] =
                        f2bf(acc[mt][nt][r] + bias[nt]);

        // t-add + h-store, 16-edge batches (32 outstanding gathers)
#pragma unroll 1
        for (int qb = 0; qb < 4; ++qb) {
            float tv[16], uv[16];
#pragma unroll
            for (int i = 0; i < 16; ++i) tv[i] = t_in [(size_t)sidx[w][qb*16+i] * 64 + lane];
#pragma unroll
            for (int i = 0; i < 16; ++i) uv[i] = t_out[(size_t)didx[w][qb*16+i] * 64 + lane];
#pragma unroll
            for (int i = 0; i < 16; ++i) {
                const int e = qb * 16 + i;
                const float v = bf2f(tile[w][e * LDP + lane]) + tv[i] + uv[i];
                hm[(size_t)(e0 + e) * 64 + lane] = f2bf(lrelu(v));
            }
        }
    }
}

// ---------------- conv3 + MLP head fused, MFMA ----------------
__global__ void __launch_bounds__(128, 2)
k_edge_mlp(const float* __restrict__ wself, const float* __restrict__ bself,
           const float* __restrict__ t_in, const float* __restrict__ t_out,
           const int* __restrict__ ei, const u16* __restrict__ hm,
           const float* __restrict__ w1, const float* __restrict__ b1,
           const float* __restrict__ w2, const float* __restrict__ b2,
           const float* __restrict__ w3, const float* __restrict__ b3,
           const float* __restrict__ w4, const float* __restrict__ b4,
           float* __restrict__ out)
{
    __shared__ alignas(16) u16 tile[WAVES][64 * LDP];
    __shared__ int sidx[WAVES][64], didx[WAVES][64];
    const int w = threadIdx.x >> 6, lane = threadIdx.x & 63;
    const int c16 = lane & 15, q4 = lane >> 4;

    short8 wfS[2][4], wf1[2][4], wf2[2][4], wf3[2][2];
    float bS[4], bv1[4], bv2[4], bv3[2];
#pragma unroll
    for (int ks = 0; ks < 2; ++ks) {
#pragma unroll
        for (int nt = 0; nt < 4; ++nt) {
            wfS[ks][nt] = bfrag(wself, 64, nt * 16 + c16, ks * 32 + q4 * 8);
            wf1[ks][nt] = bfrag(w1,    64, nt * 16 + c16, ks * 32 + q4 * 8);
            wf2[ks][nt] = bfrag(w2,    64, nt * 16 + c16, ks * 32 + q4 * 8);
        }
#pragma unroll
        for (int nt = 0; nt < 2; ++nt)
            wf3[ks][nt] = bfrag(w3, 32, nt * 16 + c16, ks * 32 + q4 * 8);
    }
#pragma unroll
    for (int nt = 0; nt < 4; ++nt) { bS[nt] = bself[nt*16+c16]; bv1[nt] = b1[nt*16+c16]; bv2[nt] = b2[nt*16+c16]; }
#pragma unroll
    for (int nt = 0; nt < 2; ++nt) bv3[nt] = b3[nt * 16 + c16];

    for (int it = 0; it < EDGE_ITERS; ++it) {
        const int tileId = (it * EDGE_BLOCKS + blockIdx.x) * WAVES + w;
        const int e0 = tileId * 64;
        sidx[w][lane] = ei[e0 + lane];
        didx[w][lane] = ei[NE + e0 + lane];

        floatx4 acc[4][4];
#pragma unroll
        for (int mt = 0; mt < 4; ++mt)
#pragma unroll
            for (int nt = 0; nt < 4; ++nt) acc[mt][nt] = (floatx4)(0.0f);

        // conv3 self-matmul (A from global bf16 h)
#pragma unroll
        for (int mt = 0; mt < 4; ++mt) {
            const short8* ap = (const short8*)(hm + (size_t)(e0 + mt * 16 + c16) * 64 + q4 * 8);
            const short8 a0 = ap[0];
            const short8 a1 = ap[4];
#pragma unroll
            for (int nt = 0; nt < 4; ++nt) {
                acc[mt][nt] = MFMA16(a0, wfS[0][nt], acc[mt][nt]);
                acc[mt][nt] = MFMA16(a1, wfS[1][nt], acc[mt][nt]);
            }
        }
#pragma unroll
        for (int mt = 0; mt < 4; ++mt)
#pragma unroll
            for (int nt = 0; nt < 4; ++nt)
#pragma unroll
                for (int r = 0; r < 4; ++r)
                    tile[w][(mt * 16 + q4 * 4 + r) * LDP + nt * 16 + c16] =
                        f2bf(acc[mt][nt][r] + bS[nt]);

        // t-add -> h3 = lrelu(.) back into LDS tile (never to HBM)
#pragma unroll 1
        for (int qb = 0; qb < 4; ++qb) {
            float tv[16], uv[16];
#pragma unroll
            for (int i = 0; i < 16; ++i) tv[i] = t_in [(size_t)sidx[w][qb*16+i] * 64 + lane];
#pragma unroll
            for (int i = 0; i < 16; ++i) uv[i] = t_out[(size_t)didx[w][qb*16+i] * 64 + lane];
#pragma unroll
            for (int i = 0; i < 16; ++i) {
                const int e = qb * 16 + i;
                const float v = bf2f(tile[w][e * LDP + lane]) + tv[i] + uv[i];
                tile[w][e * LDP + lane] = f2bf(lrelu(v));
            }
        }

        // MLP L1 (tile -> tile)
#pragma unroll
        for (int mt = 0; mt < 4; ++mt)
#pragma unroll
            for (int nt = 0; nt < 4; ++nt) acc[mt][nt] = (floatx4)(0.0f);
        mm_tile(tile[w], wf1, acc, c16, q4);
#pragma unroll
        for (int mt = 0; mt < 4; ++mt)
#pragma unroll
            for (int nt = 0; nt < 4; ++nt)
#pragma unroll
                for (int r = 0; r < 4; ++r)
                    tile[w][(mt * 16 + q4 * 4 + r) * LDP + nt * 16 + c16] =
                        f2bf(lrelu(acc[mt][nt][r] + bv1[nt]));

        // MLP L2
#pragma unroll
        for (int mt = 0; mt < 4; ++mt)
#pragma unroll
            for (int nt = 0; nt < 4; ++nt) acc[mt][nt] = (floatx4)(0.0f);
        mm_tile(tile[w], wf2, acc, c16, q4);
#pragma unroll
        for (int mt = 0; mt < 4; ++mt)
#pragma unroll
            for (int nt = 0; nt < 4; ++nt)
#pragma unroll
                for (int r = 0; r < 4; ++r)
                    tile[w][(mt * 16 + q4 * 4 + r) * LDP + nt * 16 + c16] =
                        f2bf(lrelu(acc[mt][nt][r] + bv2[nt]));

        // MLP L3: 64 -> 32
        floatx4 a3[4][2];
#pragma unroll
        for (int mt = 0; mt < 4; ++mt)
#pragma unroll
            for (int nt = 0; nt < 2; ++nt) a3[mt][nt] = (floatx4)(0.0f);
#pragma unroll
        for (int mt = 0; mt < 4; ++mt) {
            const short8 a0 = *(const short8*)(tile[w] + (mt * 16 + c16) * LDP + q4 * 8);
            const short8 a1 = *(const short8*)(tile[w] + (mt * 16 + c16) * LDP + 32 + q4 * 8);
#pragma unroll
            for (int nt = 0; nt < 2; ++nt) {
                a3[mt][nt] = MFMA16(a0, wf3[0][nt], a3[mt][nt]);
                a3[mt][nt] = MFMA16(a1, wf3[1][nt], a3[mt][nt]);
            }
        }
#pragma unroll
        for (int mt = 0; mt < 4; ++mt)
#pragma unroll
            for (int nt = 0; nt < 2; ++nt)
#pragma unroll
                for (int r = 0; r < 4; ++r)
                    tile[w][(mt * 16 + q4 * 4 + r) * LDP + nt * 16 + c16] =
                        f2bf(lrelu(a3[mt][nt][r] + bv3[nt]));

        // MLP L4: per-lane dot over own row (32 cols)
        float p0 = 0.f, p1 = 0.f, p2 = 0.f, p3 = 0.f;
#pragma unroll
        for (int k = 0; k < 32; k += 4) {
            p0 += bf2f(tile[w][lane * LDP + k + 0]) * w4[k + 0];
            p1 += bf2f(tile[w][lane * LDP + k + 1]) * w4[k + 1];
            p2 += bf2f(tile[w][lane * LDP + k + 2]) * w4[k + 2];
            p3 += bf2f(tile[w][lane * LDP + k + 3]) * w4[k + 3];
        }
        out[e0 + lane] = (p0 + p1) + (p2 + p3) + b4[0];
    }
}

extern "C" void kernel_launch(void* const* d_in, const int* in_sizes, int n_in,
                              void* d_out, int out_size, void* d_ws, size_t ws_size,
                              hipStream_t stream)
{
    const float* x      = (const float*)d_in[0];
    const int*   ei     = (const int*)  d_in[1];
    const float* raw    = (const float*)d_in[2];
    const float* wenc   = (const float*)d_in[3];
    const float* benc   = (const float*)d_in[4];
    const float* wself1 = (const float*)d_in[5];
    const float* bself1 = (const float*)d_in[6];
    const float* win1   = (const float*)d_in[7];
    const float* wout1  = (const float*)d_in[8];
    const float* wself2 = (const float*)d_in[9];
    const float* bself2 = (const float*)d_in[10];
    const float* win2   = (const float*)d_in[11];
    const float* wout2  = (const float*)d_in[12];
    const float* wself3 = (const float*)d_in[13];
    const float* bself3 = (const float*)d_in[14];
    const float* win3   = (const float*)d_in[15];
    const float* wout3  = (const float*)d_in[16];
    const float* w1 = (const float*)d_in[17]; const float* b1 = (const float*)d_in[18];
    const float* w2 = (const float*)d_in[19]; const float* b2 = (const float*)d_in[20];
    const float* w3 = (const float*)d_in[21]; const float* b3 = (const float*)d_in[22];
    const float* w4 = (const float*)d_in[23]; const float* b4 = (const float*)d_in[24];

    // ws layout: t_in|t_out (fp32) · deg/cur/off/csr (int) · hm (bf16) = 200.9MB
    float* t_in    = (float*)d_ws;
    float* t_out   = t_in + (size_t)NN * 64;
    int*   deg_in  = (int*)(t_out + (size_t)NN * 64);
    int*   deg_out = deg_in + NN;
    int*   cur_in  = deg_out + NN;
    int*   cur_out = cur_in + NN;
    int*   off_in  = cur_out + NN;
    int*   off_out = off_in + OFFSZ;
    int*   csr_in  = off_out + OFFSZ;
    int*   csr_out = csr_in + NE;
    u16*   hm      = (u16*)(csr_out + NE);             // offset 37,040,128 B (16B-aligned)

    // CSR build (once per call; ws re-poisoned before every call)
    hipMemsetAsync(deg_in, 0, (size_t)2 * NN * sizeof(int), stream);
    k_hist<<<NE / 256, 256, 0, stream>>>(ei, deg_in, deg_out);
    k_scan<<<1, 1024, 0, stream>>>(deg_in, deg_out, off_in, off_out, cur_in, cur_out);
    k_fill<<<NE / 256, 256, 0, stream>>>(ei, cur_in, cur_out, csr_in, csr_out);

    k_enc<<<EDGE_BLOCKS, 128, 0, stream>>>(x, ei, raw, wenc, benc, hm);

    k_agg<<<NN / 4, 256, 0, stream>>>(hm, off_in, csr_in, off_out, csr_out,
                                      win1, wout1, t_in, t_out);
    k_edge<<<EDGE_BLOCKS, 128, 0, stream>>>(wself1, bself1, t_in, t_out, ei, hm);

    k_agg<<<NN / 4, 256, 0, stream>>>(hm, off_in, csr_in, off_out, csr_out,
                                      win2, wout2, t_in, t_out);
    k_edge<<<EDGE_BLOCKS, 128, 0, stream>>>(wself2, bself2, t_in, t_out, ei, hm);

    k_agg<<<NN / 4, 256, 0, stream>>>(hm, off_in, csr_in, off_out, csr_out,
                                      win3, wout3, t_in, t_out);
    k_edge_mlp<<<EDGE_BLOCKS, 128, 0, stream>>>(wself3, bself3, t_in, t_out, ei, hm,
                                                w1, b1, w2, b2, w3, b3, w4, b4,
                                                (float*)d_out);
}

// Round 5
// 1309.528 us; speedup vs baseline: 2.5153x; 1.1173x over previous
//
#include <hip/hip_runtime.h>

// KidneyEdgePredictor — edge-GNN. bf16 h-storage + bf16 MFMA matmuls, fp32 gathers.
// N=50000 nodes (D=13), E=1,280,000 edges, H=64.
// encoder(27->64) -> 3x conv(scatter-mean by dst/src) -> MLP 64->64->64->32->1.
//
// R4 post-mortem: all compute kernels < 230us; k_fill 233us (atomic+scatter
// latency-bound), k_agg ~150us x6 passes (gather-latency). R5:
//  (1) k_agg: short8 row loads — 8 lanes cover one 128B bf16 row, one wave
//      loads 8 rows/instruction, 2x unrolled; channel sums via shfl_xor
//      butterfly (strides 8/16/32).
//  (2) k_hist merged into k_enc (edge-parallel already; fire-and-forget atomics).
//  (3) k_fill: 4 independent atomic chains per thread (ILP vs latency).
// k_edge / k_edge_mlp / k_scan unchanged from R4.

#define NN 50000
#define NE 1280000
#define LDP 72               // u16 pitch: 144B rows -> 16B-aligned frag reads
#define OFFSZ 50016

#define WAVES 2
#define EDGE_ITERS 4
#define EDGE_BLOCKS 2500     // 20000 tiles / (2 waves * 4 iters)

typedef unsigned int   u32;
typedef unsigned short u16;
typedef __attribute__((ext_vector_type(8))) short  short8;   // 8 bf16 (4 VGPRs)
typedef __attribute__((ext_vector_type(4))) float  floatx4;  // MFMA acc

#define MFMA16(a, b, c) __builtin_amdgcn_mfma_f32_16x16x32_bf16(a, b, c, 0, 0, 0)

__device__ __forceinline__ float lrelu(float x) { return x >= 0.0f ? x : 0.2f * x; }
__device__ __forceinline__ float bf2f(u16 u) { return __uint_as_float(((u32)u) << 16); }
__device__ __forceinline__ u16 f2bf(float f) {               // RNE
    u32 b = __float_as_uint(f);
    return (u16)((b + 0x7FFFu + ((b >> 16) & 1u)) >> 16);
}

// B-frag: lane holds B[k0..k0+7][n] of a row-major fp32 weight (ld = row stride)
__device__ __forceinline__ short8 bfrag(const float* __restrict__ W, int ld, int n, int k0) {
    short8 b;
#pragma unroll
    for (int j = 0; j < 8; ++j) b[j] = (short)f2bf(W[(k0 + j) * ld + n]);
    return b;
}

// C(64x64) += A(64x64 from bf16 LDS tile) @ B(frags): 4 mtiles x 4 ntiles x 2 ksteps
__device__ __forceinline__ void mm_tile(const u16* __restrict__ tb,
                                        const short8 wf[2][4],
                                        floatx4 acc[4][4], int c16, int q4) {
#pragma unroll
    for (int mt = 0; mt < 4; ++mt) {
        const short8 a0 = *(const short8*)(tb + (mt * 16 + c16) * LDP + q4 * 8);
        const short8 a1 = *(const short8*)(tb + (mt * 16 + c16) * LDP + 32 + q4 * 8);
#pragma unroll
        for (int nt = 0; nt < 4; ++nt) {
            acc[mt][nt] = MFMA16(a0, wf[0][nt], acc[mt][nt]);
            acc[mt][nt] = MFMA16(a1, wf[1][nt], acc[mt][nt]);
        }
    }
}

// ---------------- CSR scan + fill ----------------
__global__ void __launch_bounds__(1024)
k_scan(const int* __restrict__ deg_in, const int* __restrict__ deg_out,
       int* __restrict__ off_in, int* __restrict__ off_out,
       int* __restrict__ cur_in, int* __restrict__ cur_out)
{
    __shared__ int s[1024];
    const int tid = threadIdx.x;
    const int CH = 49;                                 // 1024*49 = 50176 >= NN
    for (int pass = 0; pass < 2; ++pass) {
        const int* deg = pass ? deg_out : deg_in;
        int* off = pass ? off_out : off_in;
        int* cur = pass ? cur_out : cur_in;
        const int lo = tid * CH, hi = min(lo + CH, NN);
        int loc = 0;
        for (int i = lo; i < hi; ++i) loc += deg[i];
        s[tid] = loc;
        __syncthreads();
        for (int d = 1; d < 1024; d <<= 1) {           // Hillis-Steele inclusive
            int t = (tid >= d) ? s[tid - d] : 0;
            __syncthreads();
            s[tid] += t;
            __syncthreads();
        }
        int run = s[tid] - loc;                        // exclusive base
        for (int i = lo; i < hi; ++i) { off[i] = run; cur[i] = run; run += deg[i]; }
        if (hi == NN && lo < NN) off[NN] = run;        // == NE
        __syncthreads();
    }
}

// 4 independent atomic+scatter chains per thread (latency-bound kernel)
__global__ void __launch_bounds__(256)
k_fill(const int* __restrict__ ei, int* __restrict__ cur_in, int* __restrict__ cur_out,
       int* __restrict__ csr_in, int* __restrict__ csr_out)
{
    const int base = (blockIdx.x * 256 + threadIdx.x) * 4;   // grid = NE/1024
    int s[4], d[4], p[4], q[4];
#pragma unroll
    for (int k = 0; k < 4; ++k) s[k] = ei[base + k];
#pragma unroll
    for (int k = 0; k < 4; ++k) d[k] = ei[NE + base + k];
#pragma unroll
    for (int k = 0; k < 4; ++k) p[k] = atomicAdd(&cur_out[s[k]], 1);
#pragma unroll
    for (int k = 0; k < 4; ++k) q[k] = atomicAdd(&cur_in[d[k]], 1);
#pragma unroll
    for (int k = 0; k < 4; ++k) csr_out[p[k]] = base + k;
#pragma unroll
    for (int k = 0; k < 4; ++k) csr_in[q[k]] = base + k;
}

// ---------------- encoder (+ degree histogram): h1 = lrelu([x_s|x_d|raw]@Wenc+b) ----------------
__global__ void __launch_bounds__(128)
k_enc(const float* __restrict__ x, const int* __restrict__ ei,
      const float* __restrict__ raw, const float* __restrict__ wenc,
      const float* __restrict__ benc, u16* __restrict__ hm,
      int* __restrict__ deg_in, int* __restrict__ deg_out)
{
    __shared__ alignas(16) u16 tile[WAVES][64 * LDP];
    const int w = threadIdx.x >> 6, lane = threadIdx.x & 63;

    for (int it = 0; it < EDGE_ITERS; ++it) {
        const int tileId = (it * EDGE_BLOCKS + blockIdx.x) * WAVES + w;
        const int e0 = tileId * 64;

        const int ms = ei[e0 + lane];
        const int md = ei[NE + e0 + lane];
        atomicAdd(&deg_out[ms], 1);                    // fused histogram
        atomicAdd(&deg_in[md], 1);

        float f[27];                                   // features in registers
#pragma unroll
        for (int j = 0; j < 13; ++j) f[j]      = x[ms * 13 + j];
#pragma unroll
        for (int j = 0; j < 13; ++j) f[13 + j] = x[md * 13 + j];
        f[26] = raw[e0 + lane];

        float acc[64];
#pragma unroll
        for (int c = 0; c < 64; ++c) acc[c] = benc[c];
        for (int k = 0; k < 27; ++k) {
            const float vk = f[k];
#pragma unroll
            for (int c = 0; c < 64; ++c) acc[c] += vk * wenc[k * 64 + c];
        }
#pragma unroll
        for (int c = 0; c < 64; ++c) tile[w][lane * LDP + c] = f2bf(lrelu(acc[c]));
        // wave-private LDS, lockstep wave64: no barrier. channel-major store.
        for (int i = 0; i < 64; ++i)
            hm[(size_t)(e0 + i) * 64 + lane] = tile[w][i * LDP + lane];
    }
}

// ---------------- per-node aggregate + transform: t = mean(h rows) @ W ----------------
// 8 consecutive lanes cover one 128B bf16 row (short8/lane): 8 rows per load inst.
__global__ void __launch_bounds__(256)
k_agg(const u16* __restrict__ hm,
      const int* __restrict__ off_in, const int* __restrict__ csr_in,
      const int* __restrict__ off_out, const int* __restrict__ csr_out,
      const float* __restrict__ w_in, const float* __restrict__ w_out,
      float* __restrict__ t_in, float* __restrict__ t_out)
{
    __shared__ float m[4][64];
    const int w = threadIdx.x >> 6, lane = threadIdx.x & 63;
    const int node = blockIdx.x * 4 + w;               // grid*4 == NN exactly
    const int rg = lane >> 3;                          // row slot in 8-batch
    const int co = (lane & 7) * 8;                     // channel octet base

    for (int pass = 0; pass < 2; ++pass) {
        const int* off = pass ? off_out : off_in;
        const int* csr = pass ? csr_out : csr_in;
        const float* wp = pass ? w_out : w_in;
        float* tp       = pass ? t_out : t_in;

        const int b0 = off[node], b1 = off[node + 1];
        float fa[8], fb[8];
#pragma unroll
        for (int c = 0; c < 8; ++c) { fa[c] = 0.f; fb[c] = 0.f; }

        int j = b0;
        for (; j + 16 <= b1; j += 16) {                // 16 rows in flight
            const int ea = csr[j + rg];
            const int eb = csr[j + 8 + rg];
            const short8 va = *(const short8*)(hm + (size_t)ea * 64 + co);
            const short8 vb = *(const short8*)(hm + (size_t)eb * 64 + co);
#pragma unroll
            for (int c = 0; c < 8; ++c) fa[c] += bf2f((u16)va[c]);
#pragma unroll
            for (int c = 0; c < 8; ++c) fb[c] += bf2f((u16)vb[c]);
        }
        for (; j < b1; j += 8) {                       // tail, predicated
            const int jj = j + rg;
            const int idx = jj < b1 ? jj : b0;         // safe (loop => b0<b1)
            const float fl = jj < b1 ? 1.f : 0.f;
            const int e = csr[idx];
            const short8 v = *(const short8*)(hm + (size_t)e * 64 + co);
#pragma unroll
            for (int c = 0; c < 8; ++c) fa[c] += fl * bf2f((u16)v[c]);
        }
#pragma unroll
        for (int c = 0; c < 8; ++c) fa[c] += fb[c];
        // butterfly across row-groups: lanes l, l^8, l^16, l^32
#pragma unroll
        for (int d = 8; d < 64; d <<= 1)
#pragma unroll
            for (int c = 0; c < 8; ++c) fa[c] += __shfl_xor(fa[c], d, 64);

        const int deg = b1 - b0;
        const float inv = 1.0f / (float)(deg > 0 ? deg : 1);
        if (lane < 8) {                                // lane l holds chans l*8..+7
#pragma unroll
            for (int c = 0; c < 8; ++c) m[w][lane * 8 + c] = fa[c] * inv;
        }
        // wave-private LDS; same-wave lgkm ordering — no barrier
        float acc = 0.f;
        for (int k = 0; k < 64; ++k) acc += m[w][k] * wp[k * 64 + lane];
        tp[(size_t)node * 64 + lane] = acc;
    }
}

// ---------------- conv edge update (layers 1,2), MFMA ----------------
__global__ void __launch_bounds__(128, 3)
k_edge(const float* __restrict__ wself, const float* __restrict__ bself,
       const float* __restrict__ t_in, const float* __restrict__ t_out,
       const int* __restrict__ ei, u16* __restrict__ hm)
{
    __shared__ alignas(16) u16 tile[WAVES][64 * LDP];
    __shared__ int sidx[WAVES][64], didx[WAVES][64];
    const int w = threadIdx.x >> 6, lane = threadIdx.x & 63;
    const int c16 = lane & 15, q4 = lane >> 4;

    short8 wf[2][4];                                   // Wself bf16 frags, resident
    float bias[4];
#pragma unroll
    for (int ks = 0; ks < 2; ++ks)
#pragma unroll
        for (int nt = 0; nt < 4; ++nt)
            wf[ks][nt] = bfrag(wself, 64, nt * 16 + c16, ks * 32 + q4 * 8);
#pragma unroll
    for (int nt = 0; nt < 4; ++nt) bias[nt] = bself[nt * 16 + c16];

    for (int it = 0; it < EDGE_ITERS; ++it) {
        const int tileId = (it * EDGE_BLOCKS + blockIdx.x) * WAVES + w;
        const int e0 = tileId * 64;
        sidx[w][lane] = ei[e0 + lane];
        didx[w][lane] = ei[NE + e0 + lane];

        floatx4 acc[4][4];
#pragma unroll
        for (int mt = 0; mt < 4; ++mt)
#pragma unroll
            for (int nt = 0; nt < 4; ++nt) acc[mt][nt] = (floatx4)(0.0f);

        // A-frags: direct 16B loads from bf16 h rows (loads consumed by MFMA
        // before this iteration's h stores issue -> no same-address hazard)
#pragma unroll
        for (int mt = 0; mt < 4; ++mt) {
            const short8* ap = (const short8*)(hm + (size_t)(e0 + mt * 16 + c16) * 64 + q4 * 8);
            const short8 a0 = ap[0];
            const short8 a1 = ap[4];                   // +32 bf16 = kstep 1
#pragma unroll
            for (int nt = 0; nt < 4; ++nt) {
                acc[mt][nt] = MFMA16(a0, wf[0][nt], acc[mt][nt]);
                acc[mt][nt] = MFMA16(a1, wf[1][nt], acc[mt][nt]);
            }
        }
        // C/D -> bf16 LDS tile (+bias), row=(lane>>4)*4+r, col=lane&15
#pragma unroll
        for (int mt = 0; mt < 4; ++mt)
#pragma unroll
            for (int nt = 0; nt < 4; ++nt)
#pragma unroll
                for (int r = 0; r < 4; ++r)
                    tile[w][(mt * 16 + q4 * 4 + r) * LDP + nt * 16 + c16] =
                        f2bf(acc[mt][nt][r] + bias[nt]);

        // t-add + h-store, 16-edge batches (32 outstanding gathers)
#pragma unroll 1
        for (int qb = 0; qb < 4; ++qb) {
            float tv[16], uv[16];
#pragma unroll
            for (int i = 0; i < 16; ++i) tv[i] = t_in [(size_t)sidx[w][qb*16+i] * 64 + lane];
#pragma unroll
            for (int i = 0; i < 16; ++i) uv[i] = t_out[(size_t)didx[w][qb*16+i] * 64 + lane];
#pragma unroll
            for (int i = 0; i < 16; ++i) {
                const int e = qb * 16 + i;
                const float v = bf2f(tile[w][e * LDP + lane]) + tv[i] + uv[i];
                hm[(size_t)(e0 + e) * 64 + lane] = f2bf(lrelu(v));
            }
        }
    }
}

// ---------------- conv3 + MLP head fused, MFMA ----------------
__global__ void __launch_bounds__(128, 2)
k_edge_mlp(const float* __restrict__ wself, const float* __restrict__ bself,
           const float* __restrict__ t_in, const float* __restrict__ t_out,
           const int* __restrict__ ei, const u16* __restrict__ hm,
           const float* __restrict__ w1, const float* __restrict__ b1,
           const float* __restrict__ w2, const float* __restrict__ b2,
           const float* __restrict__ w3, const float* __restrict__ b3,
           const float* __restrict__ w4, const float* __restrict__ b4,
           float* __restrict__ out)
{
    __shared__ alignas(16) u16 tile[WAVES][64 * LDP];
    __shared__ int sidx[WAVES][64], didx[WAVES][64];
    const int w = threadIdx.x >> 6, lane = threadIdx.x & 63;
    const int c16 = lane & 15, q4 = lane >> 4;

    short8 wfS[2][4], wf1[2][4], wf2[2][4], wf3[2][2];
    float bS[4], bv1[4], bv2[4], bv3[2];
#pragma unroll
    for (int ks = 0; ks < 2; ++ks) {
#pragma unroll
        for (int nt = 0; nt < 4; ++nt) {
            wfS[ks][nt] = bfrag(wself, 64, nt * 16 + c16, ks * 32 + q4 * 8);
            wf1[ks][nt] = bfrag(w1,    64, nt * 16 + c16, ks * 32 + q4 * 8);
            wf2[ks][nt] = bfrag(w2,    64, nt * 16 + c16, ks * 32 + q4 * 8);
        }
#pragma unroll
        for (int nt = 0; nt < 2; ++nt)
            wf3[ks][nt] = bfrag(w3, 32, nt * 16 + c16, ks * 32 + q4 * 8);
    }
#pragma unroll
    for (int nt = 0; nt < 4; ++nt) { bS[nt] = bself[nt*16+c16]; bv1[nt] = b1[nt*16+c16]; bv2[nt] = b2[nt*16+c16]; }
#pragma unroll
    for (int nt = 0; nt < 2; ++nt) bv3[nt] = b3[nt * 16 + c16];

    for (int it = 0; it < EDGE_ITERS; ++it) {
        const int tileId = (it * EDGE_BLOCKS + blockIdx.x) * WAVES + w;
        const int e0 = tileId * 64;
        sidx[w][lane] = ei[e0 + lane];
        didx[w][lane] = ei[NE + e0 + lane];

        floatx4 acc[4][4];
#pragma unroll
        for (int mt = 0; mt < 4; ++mt)
#pragma unroll
            for (int nt = 0; nt < 4; ++nt) acc[mt][nt] = (floatx4)(0.0f);

        // conv3 self-matmul (A from global bf16 h)
#pragma unroll
        for (int mt = 0; mt < 4; ++mt) {
            const short8* ap = (const short8*)(hm + (size_t)(e0 + mt * 16 + c16) * 64 + q4 * 8);
            const short8 a0 = ap[0];
            const short8 a1 = ap[4];
#pragma unroll
            for (int nt = 0; nt < 4; ++nt) {
                acc[mt][nt] = MFMA16(a0, wfS[0][nt], acc[mt][nt]);
                acc[mt][nt] = MFMA16(a1, wfS[1][nt], acc[mt][nt]);
            }
        }
#pragma unroll
        for (int mt = 0; mt < 4; ++mt)
#pragma unroll
            for (int nt = 0; nt < 4; ++nt)
#pragma unroll
                for (int r = 0; r < 4; ++r)
                    tile[w][(mt * 16 + q4 * 4 + r) * LDP + nt * 16 + c16] =
                        f2bf(acc[mt][nt][r] + bS[nt]);

        // t-add -> h3 = lrelu(.) back into LDS tile (never to HBM)
#pragma unroll 1
        for (int qb = 0; qb < 4; ++qb) {
            float tv[16], uv[16];
#pragma unroll
            for (int i = 0; i < 16; ++i) tv[i] = t_in [(size_t)sidx[w][qb*16+i] * 64 + lane];
#pragma unroll
            for (int i = 0; i < 16; ++i) uv[i] = t_out[(size_t)didx[w][qb*16+i] * 64 + lane];
#pragma unroll
            for (int i = 0; i < 16; ++i) {
                const int e = qb * 16 + i;
                const float v = bf2f(tile[w][e * LDP + lane]) + tv[i] + uv[i];
                tile[w][e * LDP + lane] = f2bf(lrelu(v));
            }
        }

        // MLP L1 (tile -> tile)
#pragma unroll
        for (int mt = 0; mt < 4; ++mt)
#pragma unroll
            for (int nt = 0; nt < 4; ++nt) acc[mt][nt] = (floatx4)(0.0f);
        mm_tile(tile[w], wf1, acc, c16, q4);
#pragma unroll
        for (int mt = 0; mt < 4; ++mt)
#pragma unroll
            for (int nt = 0; nt < 4; ++nt)
#pragma unroll
                for (int r = 0; r < 4; ++r)
                    tile[w][(mt * 16 + q4 * 4 + r) * LDP + nt * 16 + c16] =
                        f2bf(lrelu(acc[mt][nt][r] + bv1[nt]));

        // MLP L2
#pragma unroll
        for (int mt = 0; mt < 4; ++mt)
#pragma unroll
            for (int nt = 0; nt < 4; ++nt) acc[mt][nt] = (floatx4)(0.0f);
        mm_tile(tile[w], wf2, acc, c16, q4);
#pragma unroll
        for (int mt = 0; mt < 4; ++mt)
#pragma unroll
            for (int nt = 0; nt < 4; ++nt)
#pragma unroll
                for (int r = 0; r < 4; ++r)
                    tile[w][(mt * 16 + q4 * 4 + r) * LDP + nt * 16 + c16] =
                        f2bf(lrelu(acc[mt][nt][r] + bv2[nt]));

        // MLP L3: 64 -> 32
        floatx4 a3[4][2];
#pragma unroll
        for (int mt = 0; mt < 4; ++mt)
#pragma unroll
            for (int nt = 0; nt < 2; ++nt) a3[mt][nt] = (floatx4)(0.0f);
#pragma unroll
        for (int mt = 0; mt < 4; ++mt) {
            const short8 a0 = *(const short8*)(tile[w] + (mt * 16 + c16) * LDP + q4 * 8);
            const short8 a1 = *(const short8*)(tile[w] + (mt * 16 + c16) * LDP + 32 + q4 * 8);
#pragma unroll
            for (int nt = 0; nt < 2; ++nt) {
                a3[mt][nt] = MFMA16(a0, wf3[0][nt], a3[mt][nt]);
                a3[mt][nt] = MFMA16(a1, wf3[1][nt], a3[mt][nt]);
            }
        }
#pragma unroll
        for (int mt = 0; mt < 4; ++mt)
#pragma unroll
            for (int nt = 0; nt < 2; ++nt)
#pragma unroll
                for (int r = 0; r < 4; ++r)
                    tile[w][(mt * 16 + q4 * 4 + r) * LDP + nt * 16 + c16] =
                        f2bf(lrelu(a3[mt][nt][r] + bv3[nt]));

        // MLP L4: per-lane dot over own row (32 cols)
        float p0 = 0.f, p1 = 0.f, p2 = 0.f, p3 = 0.f;
#pragma unroll
        for (int k = 0; k < 32; k += 4) {
            p0 += bf2f(tile[w][lane * LDP + k + 0]) * w4[k + 0];
            p1 += bf2f(tile[w][lane * LDP + k + 1]) * w4[k + 1];
            p2 += bf2f(tile[w][lane * LDP + k + 2]) * w4[k + 2];
            p3 += bf2f(tile[w][lane * LDP + k + 3]) * w4[k + 3];
        }
        out[e0 + lane] = (p0 + p1) + (p2 + p3) + b4[0];
    }
}

extern "C" void kernel_launch(void* const* d_in, const int* in_sizes, int n_in,
                              void* d_out, int out_size, void* d_ws, size_t ws_size,
                              hipStream_t stream)
{
    const float* x      = (const float*)d_in[0];
    const int*   ei     = (const int*)  d_in[1];
    const float* raw    = (const float*)d_in[2];
    const float* wenc   = (const float*)d_in[3];
    const float* benc   = (const float*)d_in[4];
    const float* wself1 = (const float*)d_in[5];
    const float* bself1 = (const float*)d_in[6];
    const float* win1   = (const float*)d_in[7];
    const float* wout1  = (const float*)d_in[8];
    const float* wself2 = (const float*)d_in[9];
    const float* bself2 = (const float*)d_in[10];
    const float* win2   = (const float*)d_in[11];
    const float* wout2  = (const float*)d_in[12];
    const float* wself3 = (const float*)d_in[13];
    const float* bself3 = (const float*)d_in[14];
    const float* win3   = (const float*)d_in[15];
    const float* wout3  = (const float*)d_in[16];
    const float* w1 = (const float*)d_in[17]; const float* b1 = (const float*)d_in[18];
    const float* w2 = (const float*)d_in[19]; const float* b2 = (const float*)d_in[20];
    const float* w3 = (const float*)d_in[21]; const float* b3 = (const float*)d_in[22];
    const float* w4 = (const float*)d_in[23]; const float* b4 = (const float*)d_in[24];

    // ws layout: t_in|t_out (fp32) · deg/cur/off/csr (int) · hm (bf16) = 200.9MB
    float* t_in    = (float*)d_ws;
    float* t_out   = t_in + (size_t)NN * 64;
    int*   deg_in  = (int*)(t_out + (size_t)NN * 64);
    int*   deg_out = deg_in + NN;
    int*   cur_in  = deg_out + NN;
    int*   cur_out = cur_in + NN;
    int*   off_in  = cur_out + NN;
    int*   off_out = off_in + OFFSZ;
    int*   csr_in  = off_out + OFFSZ;
    int*   csr_out = csr_in + NE;
    u16*   hm      = (u16*)(csr_out + NE);             // 16B-aligned

    // zero degree arrays (ws re-poisoned before every call)
    hipMemsetAsync(deg_in, 0, (size_t)2 * NN * sizeof(int), stream);

    // encoder + fused degree histogram
    k_enc<<<EDGE_BLOCKS, 128, 0, stream>>>(x, ei, raw, wenc, benc, hm, deg_in, deg_out);

    k_scan<<<1, 1024, 0, stream>>>(deg_in, deg_out, off_in, off_out, cur_in, cur_out);
    k_fill<<<NE / 1024, 256, 0, stream>>>(ei, cur_in, cur_out, csr_in, csr_out);

    k_agg<<<NN / 4, 256, 0, stream>>>(hm, off_in, csr_in, off_out, csr_out,
                                      win1, wout1, t_in, t_out);
    k_edge<<<EDGE_BLOCKS, 128, 0, stream>>>(wself1, bself1, t_in, t_out, ei, hm);

    k_agg<<<NN / 4, 256, 0, stream>>>(hm, off_in, csr_in, off_out, csr_out,
                                      win2, wout2, t_in, t_out);
    k_edge<<<EDGE_BLOCKS, 128, 0, stream>>>(wself2, bself2, t_in, t_out, ei, hm);

    k_agg<<<NN / 4, 256, 0, stream>>>(hm, off_in, csr_in, off_out, csr_out,
                                      win3, wout3, t_in, t_out);
    k_edge_mlp<<<EDGE_BLOCKS, 128, 0, stream>>>(wself3, bself3, t_in, t_out, ei, hm,
                                                w1, b1, w2, b2, w3, b3, w4, b4,
                                                (float*)d_out);
}

// Round 6
// 1115.105 us; speedup vs baseline: 2.9539x; 1.1744x over previous
//
#include <hip/hip_runtime.h>

// KidneyEdgePredictor — edge-GNN. bf16 h-storage + bf16 MFMA matmuls, fp32 gathers.
// N=50000 nodes (D=13), E=1,280,000 edges, H=64.
// encoder(27->64) -> 3x conv(scatter-mean by dst/src) -> MLP 64->64->64->32->1.
//
// R5 post-mortem: top dispatch k_scan 220us — single-block scan, 1 CU busy,
// 255 idle. R6: hierarchical 3-kernel scan (block sums -> scan of 196 sums ->
// block-local scan + offset), all coalesced full-grid launches (~30us total).
// Everything else unchanged from R5.

#define NN 50000
#define NE 1280000
#define LDP 72               // u16 pitch: 144B rows -> 16B-aligned frag reads
#define OFFSZ 50016
#define NB 196               // scan blocks: 196*256 = 50176 >= NN

#define WAVES 2
#define EDGE_ITERS 4
#define EDGE_BLOCKS 2500     // 20000 tiles / (2 waves * 4 iters)

typedef unsigned int   u32;
typedef unsigned short u16;
typedef __attribute__((ext_vector_type(8))) short  short8;   // 8 bf16 (4 VGPRs)
typedef __attribute__((ext_vector_type(4))) float  floatx4;  // MFMA acc

#define MFMA16(a, b, c) __builtin_amdgcn_mfma_f32_16x16x32_bf16(a, b, c, 0, 0, 0)

__device__ __forceinline__ float lrelu(float x) { return x >= 0.0f ? x : 0.2f * x; }
__device__ __forceinline__ float bf2f(u16 u) { return __uint_as_float(((u32)u) << 16); }
__device__ __forceinline__ u16 f2bf(float f) {               // RNE
    u32 b = __float_as_uint(f);
    return (u16)((b + 0x7FFFu + ((b >> 16) & 1u)) >> 16);
}

// B-frag: lane holds B[k0..k0+7][n] of a row-major fp32 weight (ld = row stride)
__device__ __forceinline__ short8 bfrag(const float* __restrict__ W, int ld, int n, int k0) {
    short8 b;
#pragma unroll
    for (int j = 0; j < 8; ++j) b[j] = (short)f2bf(W[(k0 + j) * ld + n]);
    return b;
}

// C(64x64) += A(64x64 from bf16 LDS tile) @ B(frags): 4 mtiles x 4 ntiles x 2 ksteps
__device__ __forceinline__ void mm_tile(const u16* __restrict__ tb,
                                        const short8 wf[2][4],
                                        floatx4 acc[4][4], int c16, int q4) {
#pragma unroll
    for (int mt = 0; mt < 4; ++mt) {
        const short8 a0 = *(const short8*)(tb + (mt * 16 + c16) * LDP + q4 * 8);
        const short8 a1 = *(const short8*)(tb + (mt * 16 + c16) * LDP + 32 + q4 * 8);
#pragma unroll
        for (int nt = 0; nt < 4; ++nt) {
            acc[mt][nt] = MFMA16(a0, wf[0][nt], acc[mt][nt]);
            acc[mt][nt] = MFMA16(a1, wf[1][nt], acc[mt][nt]);
        }
    }
}

// ---------------- hierarchical CSR scan ----------------
// stage 1: per-block sums of both degree arrays
__global__ void __launch_bounds__(256)
k_bsum(const int* __restrict__ deg_in, const int* __restrict__ deg_out,
       int* __restrict__ bsum)
{
    __shared__ int s[256];
    const int tid = threadIdx.x;
    const int i = blockIdx.x * 256 + tid;
#pragma unroll 1
    for (int pass = 0; pass < 2; ++pass) {
        const int* deg = pass ? deg_out : deg_in;
        s[tid] = (i < NN) ? deg[i] : 0;
        __syncthreads();
        for (int d = 128; d > 0; d >>= 1) {
            if (tid < d) s[tid] += s[tid + d];
            __syncthreads();
        }
        if (tid == 0) bsum[pass * NB + blockIdx.x] = s[0];
        __syncthreads();
    }
}

// stage 2: single small block scans the 2x196 block sums -> exclusive offsets
__global__ void __launch_bounds__(256)
k_bscan(const int* __restrict__ bsum, int* __restrict__ boff)
{
    __shared__ int s[256];
    const int tid = threadIdx.x;
#pragma unroll 1
    for (int pass = 0; pass < 2; ++pass) {
        const int v = (tid < NB) ? bsum[pass * NB + tid] : 0;
        s[tid] = v;
        __syncthreads();
        for (int d = 1; d < 256; d <<= 1) {
            const int t = (tid >= d) ? s[tid - d] : 0;
            __syncthreads();
            s[tid] += t;
            __syncthreads();
        }
        if (tid < NB) boff[pass * NB + tid] = s[tid] - v;   // exclusive
        __syncthreads();
    }
}

// stage 3: block-local exclusive scan + block offset -> off & cur (coalesced)
__global__ void __launch_bounds__(256)
k_bfill(const int* __restrict__ deg_in, const int* __restrict__ deg_out,
        const int* __restrict__ boff,
        int* __restrict__ off_in, int* __restrict__ off_out,
        int* __restrict__ cur_in, int* __restrict__ cur_out)
{
    __shared__ int s[256];
    const int tid = threadIdx.x;
    const int i = blockIdx.x * 256 + tid;
#pragma unroll 1
    for (int pass = 0; pass < 2; ++pass) {
        const int* deg = pass ? deg_out : deg_in;
        int* off = pass ? off_out : off_in;
        int* cur = pass ? cur_out : cur_in;
        const int v = (i < NN) ? deg[i] : 0;
        s[tid] = v;
        __syncthreads();
        for (int d = 1; d < 256; d <<= 1) {
            const int t = (tid >= d) ? s[tid - d] : 0;
            __syncthreads();
            s[tid] += t;
            __syncthreads();
        }
        const int o = boff[pass * NB + blockIdx.x] + s[tid] - v;
        if (i < NN) { off[i] = o; cur[i] = o; }
        if (i == NN - 1) off[NN] = NE;                 // total is known
        __syncthreads();
    }
}

// 4 independent atomic+scatter chains per thread (latency-bound kernel)
__global__ void __launch_bounds__(256)
k_fill(const int* __restrict__ ei, int* __restrict__ cur_in, int* __restrict__ cur_out,
       int* __restrict__ csr_in, int* __restrict__ csr_out)
{
    const int base = (blockIdx.x * 256 + threadIdx.x) * 4;   // grid = NE/1024
    int s[4], d[4], p[4], q[4];
#pragma unroll
    for (int k = 0; k < 4; ++k) s[k] = ei[base + k];
#pragma unroll
    for (int k = 0; k < 4; ++k) d[k] = ei[NE + base + k];
#pragma unroll
    for (int k = 0; k < 4; ++k) p[k] = atomicAdd(&cur_out[s[k]], 1);
#pragma unroll
    for (int k = 0; k < 4; ++k) q[k] = atomicAdd(&cur_in[d[k]], 1);
#pragma unroll
    for (int k = 0; k < 4; ++k) csr_out[p[k]] = base + k;
#pragma unroll
    for (int k = 0; k < 4; ++k) csr_in[q[k]] = base + k;
}

// ---------------- encoder (+ degree histogram): h1 = lrelu([x_s|x_d|raw]@Wenc+b) ----------------
__global__ void __launch_bounds__(128)
k_enc(const float* __restrict__ x, const int* __restrict__ ei,
      const float* __restrict__ raw, const float* __restrict__ wenc,
      const float* __restrict__ benc, u16* __restrict__ hm,
      int* __restrict__ deg_in, int* __restrict__ deg_out)
{
    __shared__ alignas(16) u16 tile[WAVES][64 * LDP];
    const int w = threadIdx.x >> 6, lane = threadIdx.x & 63;

    for (int it = 0; it < EDGE_ITERS; ++it) {
        const int tileId = (it * EDGE_BLOCKS + blockIdx.x) * WAVES + w;
        const int e0 = tileId * 64;

        const int ms = ei[e0 + lane];
        const int md = ei[NE + e0 + lane];
        atomicAdd(&deg_out[ms], 1);                    // fused histogram
        atomicAdd(&deg_in[md], 1);

        float f[27];                                   // features in registers
#pragma unroll
        for (int j = 0; j < 13; ++j) f[j]      = x[ms * 13 + j];
#pragma unroll
        for (int j = 0; j < 13; ++j) f[13 + j] = x[md * 13 + j];
        f[26] = raw[e0 + lane];

        float acc[64];
#pragma unroll
        for (int c = 0; c < 64; ++c) acc[c] = benc[c];
        for (int k = 0; k < 27; ++k) {
            const float vk = f[k];
#pragma unroll
            for (int c = 0; c < 64; ++c) acc[c] += vk * wenc[k * 64 + c];
        }
#pragma unroll
        for (int c = 0; c < 64; ++c) tile[w][lane * LDP + c] = f2bf(lrelu(acc[c]));
        // wave-private LDS, lockstep wave64: no barrier. channel-major store.
        for (int i = 0; i < 64; ++i)
            hm[(size_t)(e0 + i) * 64 + lane] = tile[w][i * LDP + lane];
    }
}

// ---------------- per-node aggregate + transform: t = mean(h rows) @ W ----------------
// 8 consecutive lanes cover one 128B bf16 row (short8/lane): 8 rows per load inst.
__global__ void __launch_bounds__(256)
k_agg(const u16* __restrict__ hm,
      const int* __restrict__ off_in, const int* __restrict__ csr_in,
      const int* __restrict__ off_out, const int* __restrict__ csr_out,
      const float* __restrict__ w_in, const float* __restrict__ w_out,
      float* __restrict__ t_in, float* __restrict__ t_out)
{
    __shared__ float m[4][64];
    const int w = threadIdx.x >> 6, lane = threadIdx.x & 63;
    const int node = blockIdx.x * 4 + w;               // grid*4 == NN exactly
    const int rg = lane >> 3;                          // row slot in 8-batch
    const int co = (lane & 7) * 8;                     // channel octet base

    for (int pass = 0; pass < 2; ++pass) {
        const int* off = pass ? off_out : off_in;
        const int* csr = pass ? csr_out : csr_in;
        const float* wp = pass ? w_out : w_in;
        float* tp       = pass ? t_out : t_in;

        const int b0 = off[node], b1 = off[node + 1];
        float fa[8], fb[8];
#pragma unroll
        for (int c = 0; c < 8; ++c) { fa[c] = 0.f; fb[c] = 0.f; }

        int j = b0;
        for (; j + 16 <= b1; j += 16) {                // 16 rows in flight
            const int ea = csr[j + rg];
            const int eb = csr[j + 8 + rg];
            const short8 va = *(const short8*)(hm + (size_t)ea * 64 + co);
            const short8 vb = *(const short8*)(hm + (size_t)eb * 64 + co);
#pragma unroll
            for (int c = 0; c < 8; ++c) fa[c] += bf2f((u16)va[c]);
#pragma unroll
            for (int c = 0; c < 8; ++c) fb[c] += bf2f((u16)vb[c]);
        }
        for (; j < b1; j += 8) {                       // tail, predicated
            const int jj = j + rg;
            const int idx = jj < b1 ? jj : b0;         // safe (loop => b0<b1)
            const float fl = jj < b1 ? 1.f : 0.f;
            const int e = csr[idx];
            const short8 v = *(const short8*)(hm + (size_t)e * 64 + co);
#pragma unroll
            for (int c = 0; c < 8; ++c) fa[c] += fl * bf2f((u16)v[c]);
        }
#pragma unroll
        for (int c = 0; c < 8; ++c) fa[c] += fb[c];
        // butterfly across row-groups: lanes l, l^8, l^16, l^32
#pragma unroll
        for (int d = 8; d < 64; d <<= 1)
#pragma unroll
            for (int c = 0; c < 8; ++c) fa[c] += __shfl_xor(fa[c], d, 64);

        const int deg = b1 - b0;
        const float inv = 1.0f / (float)(deg > 0 ? deg : 1);
        if (lane < 8) {                                // lane l holds chans l*8..+7
#pragma unroll
            for (int c = 0; c < 8; ++c) m[w][lane * 8 + c] = fa[c] * inv;
        }
        // wave-private LDS; same-wave lgkm ordering — no barrier
        float acc = 0.f;
        for (int k = 0; k < 64; ++k) acc += m[w][k] * wp[k * 64 + lane];
        tp[(size_t)node * 64 + lane] = acc;
    }
}

// ---------------- conv edge update (layers 1,2), MFMA ----------------
__global__ void __launch_bounds__(128, 3)
k_edge(const float* __restrict__ wself, const float* __restrict__ bself,
       const float* __restrict__ t_in, const float* __restrict__ t_out,
       const int* __restrict__ ei, u16* __restrict__ hm)
{
    __shared__ alignas(16) u16 tile[WAVES][64 * LDP];
    __shared__ int sidx[WAVES][64], didx[WAVES][64];
    const int w = threadIdx.x >> 6, lane = threadIdx.x & 63;
    const int c16 = lane & 15, q4 = lane >> 4;

    short8 wf[2][4];                                   // Wself bf16 frags, resident
    float bias[4];
#pragma unroll
    for (int ks = 0; ks < 2; ++ks)
#pragma unroll
        for (int nt = 0; nt < 4; ++nt)
            wf[ks][nt] = bfrag(wself, 64, nt * 16 + c16, ks * 32 + q4 * 8);
#pragma unroll
    for (int nt = 0; nt < 4; ++nt) bias[nt] = bself[nt * 16 + c16];

    for (int it = 0; it < EDGE_ITERS; ++it) {
        const int tileId = (it * EDGE_BLOCKS + blockIdx.x) * WAVES + w;
        const int e0 = tileId * 64;
        sidx[w][lane] = ei[e0 + lane];
        didx[w][lane] = ei[NE + e0 + lane];

        floatx4 acc[4][4];
#pragma unroll
        for (int mt = 0; mt < 4; ++mt)
#pragma unroll
            for (int nt = 0; nt < 4; ++nt) acc[mt][nt] = (floatx4)(0.0f);

        // A-frags: direct 16B loads from bf16 h rows (loads consumed by MFMA
        // before this iteration's h stores issue -> no same-address hazard)
#pragma unroll
        for (int mt = 0; mt < 4; ++mt) {
            const short8* ap = (const short8*)(hm + (size_t)(e0 + mt * 16 + c16) * 64 + q4 * 8);
            const short8 a0 = ap[0];
            const short8 a1 = ap[4];                   // +32 bf16 = kstep 1
#pragma unroll
            for (int nt = 0; nt < 4; ++nt) {
                acc[mt][nt] = MFMA16(a0, wf[0][nt], acc[mt][nt]);
                acc[mt][nt] = MFMA16(a1, wf[1][nt], acc[mt][nt]);
            }
        }
        // C/D -> bf16 LDS tile (+bias), row=(lane>>4)*4+r, col=lane&15
#pragma unroll
        for (int mt = 0; mt < 4; ++mt)
#pragma unroll
            for (int nt = 0; nt < 4; ++nt)
#pragma unroll
                for (int r = 0; r < 4; ++r)
                    tile[w][(mt * 16 + q4 * 4 + r) * LDP + nt * 16 + c16] =
                        f2bf(acc[mt][nt][r] + bias[nt]);

        // t-add + h-store, 16-edge batches (32 outstanding gathers)
#pragma unroll 1
        for (int qb = 0; qb < 4; ++qb) {
            float tv[16], uv[16];
#pragma unroll
            for (int i = 0; i < 16; ++i) tv[i] = t_in [(size_t)sidx[w][qb*16+i] * 64 + lane];
#pragma unroll
            for (int i = 0; i < 16; ++i) uv[i] = t_out[(size_t)didx[w][qb*16+i] * 64 + lane];
#pragma unroll
            for (int i = 0; i < 16; ++i) {
                const int e = qb * 16 + i;
                const float v = bf2f(tile[w][e * LDP + lane]) + tv[i] + uv[i];
                hm[(size_t)(e0 + e) * 64 + lane] = f2bf(lrelu(v));
            }
        }
    }
}

// ---------------- conv3 + MLP head fused, MFMA ----------------
__global__ void __launch_bounds__(128, 2)
k_edge_mlp(const float* __restrict__ wself, const float* __restrict__ bself,
           const float* __restrict__ t_in, const float* __restrict__ t_out,
           const int* __restrict__ ei, const u16* __restrict__ hm,
           const float* __restrict__ w1, const float* __restrict__ b1,
           const float* __restrict__ w2, const float* __restrict__ b2,
           const float* __restrict__ w3, const float* __restrict__ b3,
           const float* __restrict__ w4, const float* __restrict__ b4,
           float* __restrict__ out)
{
    __shared__ alignas(16) u16 tile[WAVES][64 * LDP];
    __shared__ int sidx[WAVES][64], didx[WAVES][64];
    const int w = threadIdx.x >> 6, lane = threadIdx.x & 63;
    const int c16 = lane & 15, q4 = lane >> 4;

    short8 wfS[2][4], wf1[2][4], wf2[2][4], wf3[2][2];
    float bS[4], bv1[4], bv2[4], bv3[2];
#pragma unroll
    for (int ks = 0; ks < 2; ++ks) {
#pragma unroll
        for (int nt = 0; nt < 4; ++nt) {
            wfS[ks][nt] = bfrag(wself, 64, nt * 16 + c16, ks * 32 + q4 * 8);
            wf1[ks][nt] = bfrag(w1,    64, nt * 16 + c16, ks * 32 + q4 * 8);
            wf2[ks][nt] = bfrag(w2,    64, nt * 16 + c16, ks * 32 + q4 * 8);
        }
#pragma unroll
        for (int nt = 0; nt < 2; ++nt)
            wf3[ks][nt] = bfrag(w3, 32, nt * 16 + c16, ks * 32 + q4 * 8);
    }
#pragma unroll
    for (int nt = 0; nt < 4; ++nt) { bS[nt] = bself[nt*16+c16]; bv1[nt] = b1[nt*16+c16]; bv2[nt] = b2[nt*16+c16]; }
#pragma unroll
    for (int nt = 0; nt < 2; ++nt) bv3[nt] = b3[nt * 16 + c16];

    for (int it = 0; it < EDGE_ITERS; ++it) {
        const int tileId = (it * EDGE_BLOCKS + blockIdx.x) * WAVES + w;
        const int e0 = tileId * 64;
        sidx[w][lane] = ei[e0 + lane];
        didx[w][lane] = ei[NE + e0 + lane];

        floatx4 acc[4][4];
#pragma unroll
        for (int mt = 0; mt < 4; ++mt)
#pragma unroll
            for (int nt = 0; nt < 4; ++nt) acc[mt][nt] = (floatx4)(0.0f);

        // conv3 self-matmul (A from global bf16 h)
#pragma unroll
        for (int mt = 0; mt < 4; ++mt) {
            const short8* ap = (const short8*)(hm + (size_t)(e0 + mt * 16 + c16) * 64 + q4 * 8);
            const short8 a0 = ap[0];
            const short8 a1 = ap[4];
#pragma unroll
            for (int nt = 0; nt < 4; ++nt) {
                acc[mt][nt] = MFMA16(a0, wfS[0][nt], acc[mt][nt]);
                acc[mt][nt] = MFMA16(a1, wfS[1][nt], acc[mt][nt]);
            }
        }
#pragma unroll
        for (int mt = 0; mt < 4; ++mt)
#pragma unroll
            for (int nt = 0; nt < 4; ++nt)
#pragma unroll
                for (int r = 0; r < 4; ++r)
                    tile[w][(mt * 16 + q4 * 4 + r) * LDP + nt * 16 + c16] =
                        f2bf(acc[mt][nt][r] + bS[nt]);

        // t-add -> h3 = lrelu(.) back into LDS tile (never to HBM)
#pragma unroll 1
        for (int qb = 0; qb < 4; ++qb) {
            float tv[16], uv[16];
#pragma unroll
            for (int i = 0; i < 16; ++i) tv[i] = t_in [(size_t)sidx[w][qb*16+i] * 64 + lane];
#pragma unroll
            for (int i = 0; i < 16; ++i) uv[i] = t_out[(size_t)didx[w][qb*16+i] * 64 + lane];
#pragma unroll
            for (int i = 0; i < 16; ++i) {
                const int e = qb * 16 + i;
                const float v = bf2f(tile[w][e * LDP + lane]) + tv[i] + uv[i];
                tile[w][e * LDP + lane] = f2bf(lrelu(v));
            }
        }

        // MLP L1 (tile -> tile)
#pragma unroll
        for (int mt = 0; mt < 4; ++mt)
#pragma unroll
            for (int nt = 0; nt < 4; ++nt) acc[mt][nt] = (floatx4)(0.0f);
        mm_tile(tile[w], wf1, acc, c16, q4);
#pragma unroll
        for (int mt = 0; mt < 4; ++mt)
#pragma unroll
            for (int nt = 0; nt < 4; ++nt)
#pragma unroll
                for (int r = 0; r < 4; ++r)
                    tile[w][(mt * 16 + q4 * 4 + r) * LDP + nt * 16 + c16] =
                        f2bf(lrelu(acc[mt][nt][r] + bv1[nt]));

        // MLP L2
#pragma unroll
        for (int mt = 0; mt < 4; ++mt)
#pragma unroll
            for (int nt = 0; nt < 4; ++nt) acc[mt][nt] = (floatx4)(0.0f);
        mm_tile(tile[w], wf2, acc, c16, q4);
#pragma unroll
        for (int mt = 0; mt < 4; ++mt)
#pragma unroll
            for (int nt = 0; nt < 4; ++nt)
#pragma unroll
                for (int r = 0; r < 4; ++r)
                    tile[w][(mt * 16 + q4 * 4 + r) * LDP + nt * 16 + c16] =
                        f2bf(lrelu(acc[mt][nt][r] + bv2[nt]));

        // MLP L3: 64 -> 32
        floatx4 a3[4][2];
#pragma unroll
        for (int mt = 0; mt < 4; ++mt)
#pragma unroll
            for (int nt = 0; nt < 2; ++nt) a3[mt][nt] = (floatx4)(0.0f);
#pragma unroll
        for (int mt = 0; mt < 4; ++mt) {
            const short8 a0 = *(const short8*)(tile[w] + (mt * 16 + c16) * LDP + q4 * 8);
            const short8 a1 = *(const short8*)(tile[w] + (mt * 16 + c16) * LDP + 32 + q4 * 8);
#pragma unroll
            for (int nt = 0; nt < 2; ++nt) {
                a3[mt][nt] = MFMA16(a0, wf3[0][nt], a3[mt][nt]);
                a3[mt][nt] = MFMA16(a1, wf3[1][nt], a3[mt][nt]);
            }
        }
#pragma unroll
        for (int mt = 0; mt < 4; ++mt)
#pragma unroll
            for (int nt = 0; nt < 2; ++nt)
#pragma unroll
                for (int r = 0; r < 4; ++r)
                    tile[w][(mt * 16 + q4 * 4 + r) * LDP + nt * 16 + c16] =
                        f2bf(lrelu(a3[mt][nt][r] + bv3[nt]));

        // MLP L4: per-lane dot over own row (32 cols)
        float p0 = 0.f, p1 = 0.f, p2 = 0.f, p3 = 0.f;
#pragma unroll
        for (int k = 0; k < 32; k += 4) {
            p0 += bf2f(tile[w][lane * LDP + k + 0]) * w4[k + 0];
            p1 += bf2f(tile[w][lane * LDP + k + 1]) * w4[k + 1];
            p2 += bf2f(tile[w][lane * LDP + k + 2]) * w4[k + 2];
            p3 += bf2f(tile[w][lane * LDP + k + 3]) * w4[k + 3];
        }
        out[e0 + lane] = (p0 + p1) + (p2 + p3) + b4[0];
    }
}

extern "C" void kernel_launch(void* const* d_in, const int* in_sizes, int n_in,
                              void* d_out, int out_size, void* d_ws, size_t ws_size,
                              hipStream_t stream)
{
    const float* x      = (const float*)d_in[0];
    const int*   ei     = (const int*)  d_in[1];
    const float* raw    = (const float*)d_in[2];
    const float* wenc   = (const float*)d_in[3];
    const float* benc   = (const float*)d_in[4];
    const float* wself1 = (const float*)d_in[5];
    const float* bself1 = (const float*)d_in[6];
    const float* win1   = (const float*)d_in[7];
    const float* wout1  = (const float*)d_in[8];
    const float* wself2 = (const float*)d_in[9];
    const float* bself2 = (const float*)d_in[10];
    const float* win2   = (const float*)d_in[11];
    const float* wout2  = (const float*)d_in[12];
    const float* wself3 = (const float*)d_in[13];
    const float* bself3 = (const float*)d_in[14];
    const float* win3   = (const float*)d_in[15];
    const float* wout3  = (const float*)d_in[16];
    const float* w1 = (const float*)d_in[17]; const float* b1 = (const float*)d_in[18];
    const float* w2 = (const float*)d_in[19]; const float* b2 = (const float*)d_in[20];
    const float* w3 = (const float*)d_in[21]; const float* b3 = (const float*)d_in[22];
    const float* w4 = (const float*)d_in[23]; const float* b4 = (const float*)d_in[24];

    // ws layout: t_in|t_out (fp32) · deg/cur/off/csr/bsum/boff (int) · hm (bf16)
    float* t_in    = (float*)d_ws;
    float* t_out   = t_in + (size_t)NN * 64;
    int*   deg_in  = (int*)(t_out + (size_t)NN * 64);
    int*   deg_out = deg_in + NN;
    int*   cur_in  = deg_out + NN;
    int*   cur_out = cur_in + NN;
    int*   off_in  = cur_out + NN;
    int*   off_out = off_in + OFFSZ;
    int*   csr_in  = off_out + OFFSZ;
    int*   csr_out = csr_in + NE;
    int*   bsum    = csr_out + NE;                     // 2*NB ints
    int*   boff    = bsum + 512;                       // 2*NB ints (512-pad)
    u16*   hm      = (u16*)(boff + 512);               // 16B-aligned

    // zero degree arrays (ws re-poisoned before every call)
    hipMemsetAsync(deg_in, 0, (size_t)2 * NN * sizeof(int), stream);

    // encoder + fused degree histogram
    k_enc<<<EDGE_BLOCKS, 128, 0, stream>>>(x, ei, raw, wenc, benc, hm, deg_in, deg_out);

    // hierarchical scan (R6: was single-block k_scan, 220us on 1 CU)
    k_bsum <<<NB, 256, 0, stream>>>(deg_in, deg_out, bsum);
    k_bscan<<<1,  256, 0, stream>>>(bsum, boff);
    k_bfill<<<NB, 256, 0, stream>>>(deg_in, deg_out, boff, off_in, off_out, cur_in, cur_out);
    k_fill<<<NE / 1024, 256, 0, stream>>>(ei, cur_in, cur_out, csr_in, csr_out);

    k_agg<<<NN / 4, 256, 0, stream>>>(hm, off_in, csr_in, off_out, csr_out,
                                      win1, wout1, t_in, t_out);
    k_edge<<<EDGE_BLOCKS, 128, 0, stream>>>(wself1, bself1, t_in, t_out, ei, hm);

    k_agg<<<NN / 4, 256, 0, stream>>>(hm, off_in, csr_in, off_out, csr_out,
                                      win2, wout2, t_in, t_out);
    k_edge<<<EDGE_BLOCKS, 128, 0, stream>>>(wself2, bself2, t_in, t_out, ei, hm);

    k_agg<<<NN / 4, 256, 0, stream>>>(hm, off_in, csr_in, off_out, csr_out,
                                      win3, wout3, t_in, t_out);
    k_edge_mlp<<<EDGE_BLOCKS, 128, 0, stream>>>(wself3, bself3, t_in, t_out, ei, hm,
                                                w1, b1, w2, b2, w3, b3, w4, b4,
                                                (float*)d_out);
}